// Round 1
// baseline (329.780 us; speedup 1.0000x reference)
//
#include <hip/hip_runtime.h>
#include <hip/hip_bf16.h>
#include <stdint.h>

typedef short bf16x8 __attribute__((ext_vector_type(8)));
typedef float f32x4 __attribute__((ext_vector_type(4)));
typedef unsigned short u16x4 __attribute__((ext_vector_type(4)));

#define GLOAD16(g, l) __builtin_amdgcn_global_load_lds( \
    (const __attribute__((address_space(1))) void*)(g), \
    (__attribute__((address_space(3))) void*)(l), 16, 0, 0)

__device__ __forceinline__ unsigned short f2bf(float f) {
  unsigned u = __float_as_uint(f);
  unsigned r = (u + 0x7fffu + ((u >> 16) & 1u)) >> 16;
  return (unsigned short)r;
}

// ---------------- prep: W_t[f][k2] bf16 (k2 = c*32+e) + wcomb[m][c] f32 (c<32:left, else right)
__global__ __launch_bounds__(256) void prep_k(
    const float* __restrict__ lw, const float* __restrict__ rw,
    const float* __restrict__ ow, unsigned short* __restrict__ Wt,
    float* __restrict__ wcomb) {
  int idx = blockIdx.x * 256 + threadIdx.x;
  if (idx < 131072) {
    int f = idx >> 10, k2 = idx & 1023;
    Wt[idx] = f2bf(ow[(k2 << 7) + f]);
  }
  if (idx < 16384) {
    int m = idx >> 6, c = idx & 63;
    wcomb[idx] = (c < 32) ? lw[m * 32 + c] : rw[m * 32 + (c - 32)];
  }
}

// ---------------- norm[b][d] = sum_a mask[a,b]*mask[a,d]
__global__ __launch_bounds__(256) void norm_k(const float* __restrict__ mask,
                                              float* __restrict__ nrm) {
  int b = blockIdx.x, d = threadIdx.x;
  float s = 0.f;
  for (int a = 0; a < 512; ++a)
    s += mask[a * 256 + b] * mask[a * 256 + d];
  nrm[(b << 8) + d] = s;
}

// ---------------- fused LayerNorm + left/right projections
// block: (achunk, b); 64 a-rows of one b. Outputs Lt[b*32+c][a], Rt[b*32+c][a] bf16.
__global__ __launch_bounds__(256) void ln_proj(
    const float* __restrict__ act, const float* __restrict__ mask,
    const float* __restrict__ lns, const float* __restrict__ lno,
    const float* __restrict__ lb, const float* __restrict__ rb,
    const float* __restrict__ wcomb, unsigned short* __restrict__ Lt,
    unsigned short* __restrict__ Rt) {
  __shared__ float xs[64 * 256];
  __shared__ float part[64 * 4 * 2];
  __shared__ float muA[64], rsA[64];
  const int t = threadIdx.x;
  const int b = blockIdx.y;
  const int a0 = blockIdx.x << 6;
  const float* abase = act + ((size_t)a0 * 256 + b) * 256;

  // stage 64 rows x 256 f32
  #pragma unroll
  for (int i = 0; i < 16; ++i) {
    const int r = (i << 2) + (t >> 6);
    const int c4 = t & 63;
    const f32x4 v = *(const f32x4*)(abase + (size_t)r * 65536 + (c4 << 2));
    *(f32x4*)&xs[(r << 8) + (c4 << 2)] = v;
  }
  __syncthreads();
  // LN partial sums: 4 threads per row
  {
    const int r = t >> 2, q = t & 3;
    float s = 0.f, sq = 0.f;
    const f32x4* xr = (const f32x4*)&xs[(r << 8) + (q << 6)];
    #pragma unroll
    for (int i = 0; i < 16; ++i) {
      f32x4 v = xr[i];
      s += v[0] + v[1] + v[2] + v[3];
      sq += v[0] * v[0] + v[1] * v[1] + v[2] * v[2] + v[3] * v[3];
    }
    part[(((r << 2) + q) << 1) + 0] = s;
    part[(((r << 2) + q) << 1) + 1] = sq;
  }
  __syncthreads();
  if (t < 64) {
    float s = part[t * 8] + part[t * 8 + 2] + part[t * 8 + 4] + part[t * 8 + 6];
    float sq = part[t * 8 + 1] + part[t * 8 + 3] + part[t * 8 + 5] + part[t * 8 + 7];
    float mu = s * (1.f / 256.f);
    float var = sq * (1.f / 256.f) - mu * mu;
    muA[t] = mu;
    rsA[t] = rsqrtf(var + 1e-5f);
  }
  __syncthreads();
  // normalize in place (column t)
  {
    const float sc = lns[t], of = lno[t];
    #pragma unroll 8
    for (int r = 0; r < 64; ++r) {
      xs[(r << 8) + t] = (xs[(r << 8) + t] - muA[r]) * rsA[r] * sc + of;
    }
  }
  __syncthreads();
  // projection: thread handles 4 c x 4 r
  const int c0 = (t & 15) << 2;
  const int rg = t >> 4;
  float acc[4][4];
  #pragma unroll
  for (int i = 0; i < 4; ++i)
    #pragma unroll
    for (int j = 0; j < 4; ++j) acc[i][j] = 0.f;

  for (int mc = 0; mc < 64; ++mc) {
    f32x4 xv[4], wv[4];
    #pragma unroll
    for (int rr = 0; rr < 4; ++rr)
      xv[rr] = *(const f32x4*)&xs[(((rg << 2) + rr) << 8) + (mc << 2)];
    #pragma unroll
    for (int i = 0; i < 4; ++i)
      wv[i] = *(const f32x4*)&wcomb[(((mc << 2) + i) << 6) + c0];
    #pragma unroll
    for (int rr = 0; rr < 4; ++rr)
      #pragma unroll
      for (int i = 0; i < 4; ++i)
        #pragma unroll
        for (int cc = 0; cc < 4; ++cc)
          acc[rr][cc] += xv[rr][i] * wv[i][cc];
  }
  // bias, mask, pack to bf16, store 4 consecutive a per c
  const bool isL = (c0 < 32);
  float bias[4];
  #pragma unroll
  for (int cc = 0; cc < 4; ++cc)
    bias[cc] = isL ? lb[c0 + cc] : rb[c0 + cc - 32];
  float mk[4];
  #pragma unroll
  for (int rr = 0; rr < 4; ++rr)
    mk[rr] = mask[(size_t)(a0 + (rg << 2) + rr) * 256 + b];
  unsigned short* dst = isL ? Lt : Rt;
  const int cB = isL ? c0 : (c0 - 32);
  #pragma unroll
  for (int cc = 0; cc < 4; ++cc) {
    u16x4 pk;
    #pragma unroll
    for (int rr = 0; rr < 4; ++rr)
      pk[rr] = f2bf((acc[rr][cc] + bias[cc]) * mk[rr]);
    *(u16x4*)&dst[(size_t)(b * 32 + cB + cc) * 512 + a0 + (rg << 2)] = pk;
  }
}

// ---------------- main: op[m,n] = sum_k Lt[m,k]*Rt[n,k] (128x128 tile, K=512),
// fused epilogue: op-tile -> LDS bf16 -> contract with W_t -> out[b,d,f]
__global__ __launch_bounds__(256) void gemm_fused(
    const unsigned short* __restrict__ Lt, const unsigned short* __restrict__ Rt,
    const unsigned short* __restrict__ Wt, const float* __restrict__ nrm,
    const float* __restrict__ outb, float* __restrict__ out) {
  __shared__ char smem[32768];  // A tile 16KB | B tile 16KB ; reused as opvec[16][1024] bf16
  const int tid = threadIdx.x;
  const int lane = tid & 63;
  const int w = tid >> 6;
  const int wm = w >> 1, wn = w & 1;
  const int mb = blockIdx.x & 63, nb = blockIdx.x >> 6;
  const size_t m0 = (size_t)mb * 128, n0 = (size_t)nb * 128;

  f32x4 acc[4][4];
  #pragma unroll
  for (int i = 0; i < 4; ++i)
    #pragma unroll
    for (int j = 0; j < 4; ++j) acc[i][j] = (f32x4){0.f, 0.f, 0.f, 0.f};

  const int r_loc = lane >> 3, slot = lane & 7;
  const int gcol = ((slot ^ r_loc) << 3);  // XOR-swizzled source column (elements)
  const int mrow = lane & 15, g = lane >> 4;

  for (int t = 0; t < 8; ++t) {
    const int k0 = t << 6;
    __syncthreads();
    #pragma unroll
    for (int i = 0; i < 4; ++i) {
      const int ci = (w << 2) + i;           // chunk 0..15, 8 rows each
      const int row = (ci << 3) + r_loc;
      GLOAD16(Lt + (m0 + row) * 512 + k0 + gcol, smem + (ci << 10));
      GLOAD16(Rt + (n0 + row) * 512 + k0 + gcol, smem + 16384 + (ci << 10));
    }
    __syncthreads();
    #pragma unroll
    for (int kk = 0; kk < 2; ++kk) {
      bf16x8 af[4], bfr[4];
      #pragma unroll
      for (int mi = 0; mi < 4; ++mi) {
        const int row = (wm << 6) + (mi << 4) + mrow;
        const int off = (row << 7) + ((((kk << 2) + g) ^ (row & 7)) << 4);
        af[mi] = *(const bf16x8*)(smem + off);
      }
      #pragma unroll
      for (int ni = 0; ni < 4; ++ni) {
        const int row = (wn << 6) + (ni << 4) + mrow;
        const int off = (row << 7) + ((((kk << 2) + g) ^ (row & 7)) << 4);
        bfr[ni] = *(const bf16x8*)(smem + 16384 + off);
      }
      #pragma unroll
      for (int mi = 0; mi < 4; ++mi)
        #pragma unroll
        for (int ni = 0; ni < 4; ++ni)
          acc[mi][ni] = __builtin_amdgcn_mfma_f32_16x16x32_bf16(
              af[mi], bfr[ni], acc[mi][ni], 0, 0, 0);
    }
  }

  __syncthreads();
  // scatter op tile into opvec[p][k2] bf16 (swizzled): p = b_loc*4+d_loc, k2 = c*32+e
  #pragma unroll
  for (int mi = 0; mi < 4; ++mi) {
    #pragma unroll
    for (int ni = 0; ni < 4; ++ni) {
      #pragma unroll
      for (int q = 0; q < 4; ++q) {
        const int mt = (wm << 6) + (mi << 4) + (g << 2) + q;
        const int nt = (wn << 6) + (ni << 4) + mrow;
        const int p = ((mt >> 5) << 2) | (nt >> 5);
        const int k2 = ((mt & 31) << 5) | (nt & 31);
        const int byt = ((p << 11) + (k2 << 1)) ^ ((p & 7) << 4);
        *(unsigned short*)(smem + byt) = f2bf(acc[mi][ni][q]);
      }
    }
  }
  __syncthreads();

  // stage 2: out[p][f] = sum_k2 opvec[p][k2] * W_t[f][k2]; wave handles 32 f
  f32x4 acc2[2];
  acc2[0] = (f32x4){0.f, 0.f, 0.f, 0.f};
  acc2[1] = (f32x4){0.f, 0.f, 0.f, 0.f};
  const int fw = w << 5;
  #pragma unroll 4
  for (int kk2 = 0; kk2 < 32; ++kk2) {
    const int colb = ((kk2 << 5) + (g << 3)) << 1;
    const int abyte = ((mrow << 11) + colb) ^ ((mrow & 7) << 4);
    bf16x8 a2 = *(const bf16x8*)(smem + abyte);
    #pragma unroll
    for (int ni2 = 0; ni2 < 2; ++ni2) {
      const int f = fw + (ni2 << 4) + mrow;
      bf16x8 b2 = *(const bf16x8*)(Wt + f * 1024 + (kk2 << 5) + (g << 3));
      acc2[ni2] = __builtin_amdgcn_mfma_f32_16x16x32_bf16(a2, b2, acc2[ni2], 0, 0, 0);
    }
  }

  // epilogue: bias, /(eps+norm), store. C/D row = g*4+q = p, col = f.
  #pragma unroll
  for (int ni2 = 0; ni2 < 2; ++ni2) {
    #pragma unroll
    for (int q = 0; q < 4; ++q) {
      const int f = fw + (ni2 << 4) + mrow;
      const int b = (mb << 2) + g;
      const int d = (nb << 2) + q;
      float v = acc2[ni2][q] + outb[f];
      v = v / (1e-3f + nrm[(b << 8) + d]);
      out[(size_t)((b << 8) + d) * 128 + f] = v;
    }
  }
}

extern "C" void kernel_launch(void* const* d_in, const int* in_sizes, int n_in,
                              void* d_out, int out_size, void* d_ws, size_t ws_size,
                              hipStream_t stream) {
  const float* act = (const float*)d_in[0];
  const float* mask = (const float*)d_in[1];
  const float* lns = (const float*)d_in[2];
  const float* lno = (const float*)d_in[3];
  const float* lw = (const float*)d_in[4];
  const float* lb = (const float*)d_in[5];
  const float* rw = (const float*)d_in[6];
  const float* rbv = (const float*)d_in[7];
  const float* ow = (const float*)d_in[8];
  const float* ob = (const float*)d_in[9];
  float* out = (float*)d_out;
  char* ws = (char*)d_ws;

  unsigned short* Lt = (unsigned short*)(ws);              // 8192*512 bf16 = 8 MB
  unsigned short* Rt = (unsigned short*)(ws + 8388608);    // 8 MB
  unsigned short* Wt = (unsigned short*)(ws + 16777216);   // 128*1024 bf16 = 256 KB
  float* wcomb = (float*)(ws + 17039360);                  // 256*64 f32 = 64 KB
  float* nrm = (float*)(ws + 17104896);                    // 256*256 f32 = 256 KB

  hipLaunchKernelGGL(prep_k, dim3(576), dim3(256), 0, stream, lw, rw, ow, Wt, wcomb);
  hipLaunchKernelGGL(norm_k, dim3(256), dim3(256), 0, stream, mask, nrm);
  hipLaunchKernelGGL(ln_proj, dim3(8, 256), dim3(256), 0, stream,
                     act, mask, lns, lno, lb, rbv, wcomb, Lt, Rt);
  hipLaunchKernelGGL(gemm_fused, dim3(4096), dim3(256), 0, stream,
                     Lt, Rt, Wt, nrm, ob, out);
}

// Round 2
// 269.455 us; speedup vs baseline: 1.2239x; 1.2239x over previous
//
#include <hip/hip_runtime.h>
#include <hip/hip_bf16.h>
#include <stdint.h>

typedef short bf16x8 __attribute__((ext_vector_type(8)));
typedef float f32x4 __attribute__((ext_vector_type(4)));
typedef unsigned short u16x4 __attribute__((ext_vector_type(4)));
typedef unsigned short u16x8 __attribute__((ext_vector_type(8)));

#define GLOAD16(g, l) __builtin_amdgcn_global_load_lds( \
    (const __attribute__((address_space(1))) void*)(g), \
    (__attribute__((address_space(3))) void*)(l), 16, 0, 0)

__device__ __forceinline__ unsigned short f2bf(float f) {
  unsigned u = __float_as_uint(f);
  unsigned r = (u + 0x7fffu + ((u >> 16) & 1u)) >> 16;
  return (unsigned short)r;
}

// ---------------- prep: Wt[f][k2'] bf16 with k2' = e*32 + c ; wcombT[c][m] bf16
__global__ __launch_bounds__(256) void prep_k(
    const float* __restrict__ lw, const float* __restrict__ rw,
    const float* __restrict__ ow, unsigned short* __restrict__ Wt,
    unsigned short* __restrict__ wcombT) {
  int idx = blockIdx.x * 256 + threadIdx.x;
  if (idx < 131072) {
    int f = idx >> 10, k2 = idx & 1023;
    int e = k2 >> 5, c = k2 & 31;
    Wt[idx] = f2bf(ow[(size_t)((c << 5) + e) * 128 + f]);
  }
  if (idx < 16384) {
    int c = idx >> 8, m = idx & 255;
    wcombT[idx] = f2bf(c < 32 ? lw[m * 32 + c] : rw[m * 32 + (c - 32)]);
  }
}

// ---------------- norm[b][d] = sum_a mask[a,b]*mask[a,d]
__global__ __launch_bounds__(256) void norm_k(const float* __restrict__ mask,
                                              float* __restrict__ nrm) {
  int b = blockIdx.x, d = threadIdx.x;
  float s = 0.f;
  for (int a = 0; a < 512; ++a)
    s += mask[a * 256 + b] * mask[a * 256 + d];
  nrm[(b << 8) + d] = s;
}

// ---------------- fused LayerNorm + projections via MFMA
// block (a-chunk, b): 64 a-rows of one b. A = x_hat [64][256] bf16 (LDS, swz),
// B = wcombT [64][256] bf16 (LDS, swz). C[64 a][64 c] -> masked, bias, store
// transposed to Lt/Rt[b*32+c][a].
__global__ __launch_bounds__(256) void ln_proj(
    const float* __restrict__ act, const float* __restrict__ mask,
    const float* __restrict__ lns, const float* __restrict__ lno,
    const float* __restrict__ lb, const float* __restrict__ rb,
    const unsigned short* __restrict__ wcombT,
    unsigned short* __restrict__ Lt, unsigned short* __restrict__ Rt) {
  __shared__ char smem[65536];  // A 32KB | B 32KB
  const int tid = threadIdx.x;
  const int lane = tid & 63;
  const int w = tid >> 6;
  const int b = blockIdx.y;
  const int a0 = blockIdx.x << 6;
  const int r = tid >> 2;  // a-local row 0..63
  const int q = tid & 3;   // quarter of the 256-wide m row

  // load 64 f32 of the row into regs
  f32x4 xv[16];
  const float* src = act + ((size_t)(a0 + r) * 256 + b) * 256 + (q << 6);
  #pragma unroll
  for (int i = 0; i < 16; ++i) xv[i] = *(const f32x4*)(src + (i << 2));
  float s = 0.f, sq = 0.f;
  #pragma unroll
  for (int i = 0; i < 16; ++i) {
    f32x4 v = xv[i];
    s += v[0] + v[1] + v[2] + v[3];
    sq += v[0] * v[0] + v[1] * v[1] + v[2] * v[2] + v[3] * v[3];
  }
  s += __shfl_xor(s, 1); sq += __shfl_xor(sq, 1);
  s += __shfl_xor(s, 2); sq += __shfl_xor(sq, 2);
  const float mu = s * (1.f / 256.f);
  const float rs = rsqrtf(sq * (1.f / 256.f) - mu * mu + 1e-5f);

  // stage B tile (wcombT rows = c), swizzled
  {
    const unsigned short* wsrc = wcombT + r * 256 + (q << 6);
    #pragma unroll
    for (int i = 0; i < 8; ++i) {
      u16x8 v = *(const u16x8*)(wsrc + (i << 3));
      const int c = (q << 3) + i;
      *(u16x8*)(smem + 32768 + (r << 9) + ((c ^ (r & 7)) << 4)) = v;
    }
  }
  // scale + convert + stage A tile, swizzled
  #pragma unroll
  for (int i = 0; i < 8; ++i) {
    u16x8 pk;
    #pragma unroll
    for (int h = 0; h < 2; ++h) {
      const int b4 = (i << 1) + h;
      const f32x4 sc = *(const f32x4*)(lns + (q << 6) + (b4 << 2));
      const f32x4 of = *(const f32x4*)(lno + (q << 6) + (b4 << 2));
      const f32x4 v = xv[b4];
      #pragma unroll
      for (int j = 0; j < 4; ++j)
        pk[(h << 2) + j] = f2bf((v[j] - mu) * rs * sc[j] + of[j]);
    }
    const int c = (q << 3) + i;
    *(u16x8*)(smem + (r << 9) + ((c ^ (r & 7)) << 4)) = pk;
  }
  __syncthreads();

  // MFMA 64x64x256: wave (wr, wc) owns 32 a x 32 c
  const int wr = w >> 1, wc = w & 1;
  const int mrow = lane & 15, g = lane >> 4;
  f32x4 acc[2][2];
  #pragma unroll
  for (int i = 0; i < 2; ++i)
    #pragma unroll
    for (int j = 0; j < 2; ++j) acc[i][j] = (f32x4){0.f, 0.f, 0.f, 0.f};
  #pragma unroll
  for (int kk = 0; kk < 8; ++kk) {
    bf16x8 af[2], bfr[2];
    #pragma unroll
    for (int mi = 0; mi < 2; ++mi) {
      const int row = (wr << 5) + (mi << 4) + mrow;
      af[mi] = *(const bf16x8*)(smem + (row << 9) + ((((kk << 2) + g) ^ (row & 7)) << 4));
    }
    #pragma unroll
    for (int ni = 0; ni < 2; ++ni) {
      const int row = (wc << 5) + (ni << 4) + mrow;
      bfr[ni] = *(const bf16x8*)(smem + 32768 + (row << 9) + ((((kk << 2) + g) ^ (row & 7)) << 4));
    }
    #pragma unroll
    for (int mi = 0; mi < 2; ++mi)
      #pragma unroll
      for (int ni = 0; ni < 2; ++ni)
        acc[mi][ni] = __builtin_amdgcn_mfma_f32_16x16x32_bf16(af[mi], bfr[ni], acc[mi][ni], 0, 0, 0);
  }

  // epilogue: bias, mask, pack, transposed store
  #pragma unroll
  for (int ni = 0; ni < 2; ++ni) {
    const int c31 = (ni << 4) + mrow;
    const float bias = (wc == 0) ? lb[c31] : rb[c31];
    unsigned short* dst = (wc == 0) ? Lt : Rt;
    #pragma unroll
    for (int mi = 0; mi < 2; ++mi) {
      u16x4 pk;
      #pragma unroll
      for (int qq = 0; qq < 4; ++qq) {
        const int ar = (wr << 5) + (mi << 4) + (g << 2) + qq;
        const float mk = mask[(size_t)(a0 + ar) * 256 + b];
        pk[qq] = f2bf((acc[mi][ni][qq] + bias) * mk);
      }
      *(u16x4*)(dst + (size_t)(b * 32 + c31) * 512 + a0 + (wr << 5) + (mi << 4) + (g << 2)) = pk;
    }
  }
}

// ---------------- staging helper for gemm (pre-swizzled source, linear dest)
__device__ __forceinline__ void stage1(const unsigned short* __restrict__ Lt,
                                       const unsigned short* __restrict__ Rt,
                                       char* base, size_t m0, size_t n0, int k0,
                                       int w, int srow, int scol) {
  #pragma unroll
  for (int i = 0; i < 4; ++i) {
    const int ci = (w << 2) + i;        // 0..31, 8 rows each
    const int row = (ci << 3) + srow;
    GLOAD16(Lt + (m0 + row) * 512 + k0 + scol, base + (ci << 10));
    GLOAD16(Rt + (n0 + row) * 512 + k0 + scol, base + 32768 + (ci << 10));
  }
}

// ---------------- main GEMM: 256x256 tile, 8 waves, BK=64, 2-phase dbuf.
// Fused epilogue: op tile -> opvec[64][1024] bf16 (LDS reuse) -> x Wt -> out.
__global__ __launch_bounds__(512, 2) void gemm_fused(
    const unsigned short* __restrict__ Lt, const unsigned short* __restrict__ Rt,
    const unsigned short* __restrict__ Wt, const float* __restrict__ nrm,
    const float* __restrict__ outb, float* __restrict__ out) {
  __shared__ char smem[131072];  // dbuf: buf b at b*65536 (A 32KB | B 32KB); reused as opvec
  const int tid = threadIdx.x;
  const int lane = tid & 63;
  const int w = tid >> 6;              // 0..7
  const int wr = w >> 2, wc = w & 3;   // 2 x 4 wave grid, wave owns 128m x 64n
  const int mrow = lane & 15, g = lane >> 4;

  // XCD-aware swizzle (1024 % 8 == 0)
  const int bid = blockIdx.x;
  const int wg = (bid & 7) * 128 + (bid >> 3);
  const int mb = wg & 31, nb = wg >> 5;
  const size_t m0 = (size_t)mb << 8, n0 = (size_t)nb << 8;

  const int srow = lane >> 3;
  const int scol = ((lane & 7) ^ srow) << 3;  // pre-swizzled source k offset

  f32x4 acc[8][4];
  #pragma unroll
  for (int i = 0; i < 8; ++i)
    #pragma unroll
    for (int j = 0; j < 4; ++j) acc[i][j] = (f32x4){0.f, 0.f, 0.f, 0.f};

  stage1(Lt, Rt, smem, m0, n0, 0, w, srow, scol);
  __syncthreads();

  for (int t = 0; t < 8; ++t) {
    if (t < 7) stage1(Lt, Rt, smem + (((t + 1) & 1) << 16), m0, n0, (t + 1) << 6, w, srow, scol);
    const char* base = smem + ((t & 1) << 16);
    __builtin_amdgcn_s_setprio(1);
    #pragma unroll
    for (int kk = 0; kk < 2; ++kk) {
      bf16x8 bfr[4];
      #pragma unroll
      for (int ni = 0; ni < 4; ++ni) {
        const int row = (wc << 6) + (ni << 4) + mrow;
        bfr[ni] = *(const bf16x8*)(base + 32768 + (row << 7) + ((((kk << 2) + g) ^ (row & 7)) << 4));
      }
      #pragma unroll
      for (int mi = 0; mi < 8; ++mi) {
        const int row = (wr << 7) + (mi << 4) + mrow;
        const bf16x8 af = *(const bf16x8*)(base + (row << 7) + ((((kk << 2) + g) ^ (row & 7)) << 4));
        #pragma unroll
        for (int ni = 0; ni < 4; ++ni)
          acc[mi][ni] = __builtin_amdgcn_mfma_f32_16x16x32_bf16(af, bfr[ni], acc[mi][ni], 0, 0, 0);
      }
    }
    __builtin_amdgcn_s_setprio(0);
    __syncthreads();
  }

  // scatter op tile -> opvec[p][k2'] bf16, p = bloc*8+dloc, k2' = e*32+c, dual-XOR swz
  #pragma unroll
  for (int mi = 0; mi < 8; ++mi) {
    #pragma unroll
    for (int ni = 0; ni < 4; ++ni) {
      const int p = (((wr << 2) + (mi >> 1)) << 3) | ((wc << 1) + (ni >> 1));
      const int ow_ = ((ni & 1) << 10) + (mrow << 6) + ((mi & 1) << 5) + (g << 3);
      u16x4 pk;
      #pragma unroll
      for (int qq = 0; qq < 4; ++qq) pk[qq] = f2bf(acc[mi][ni][qq]);
      *(u16x4*)(smem + (p << 11) + (ow_ ^ ((p & 7) << 4) ^ (((ow_ >> 7) & 7) << 4))) = pk;
    }
  }
  __syncthreads();

  // stage 2: out2[p][f] = sum_k2' opvec[p][k2'] * Wt[f][k2']
  const int pf = w >> 1, fh = w & 1;  // wave: 16 p-rows x 64 f
  f32x4 acc2[4];
  #pragma unroll
  for (int i = 0; i < 4; ++i) acc2[i] = (f32x4){0.f, 0.f, 0.f, 0.f};
  const int prow = (pf << 4) + mrow;
  #pragma unroll 4
  for (int kk2 = 0; kk2 < 32; ++kk2) {
    const int orr = (kk2 << 6) + (g << 4);
    const bf16x8 a2 = *(const bf16x8*)(smem + (prow << 11) +
        (orr ^ ((prow & 7) << 4) ^ (((orr >> 7) & 7) << 4)));
    #pragma unroll
    for (int ni2 = 0; ni2 < 4; ++ni2) {
      const int f = (fh << 6) + (ni2 << 4) + mrow;
      const bf16x8 b2 = *(const bf16x8*)(Wt + (size_t)f * 1024 + (kk2 << 5) + (g << 3));
      acc2[ni2] = __builtin_amdgcn_mfma_f32_16x16x32_bf16(a2, b2, acc2[ni2], 0, 0, 0);
    }
  }

  // epilogue: bias, /(eps+norm), store (16 lanes contiguous in f)
  #pragma unroll
  for (int ni2 = 0; ni2 < 4; ++ni2) {
    #pragma unroll
    for (int qq = 0; qq < 4; ++qq) {
      const int prow2 = (pf << 4) + (g << 2) + qq;
      const int f = (fh << 6) + (ni2 << 4) + mrow;
      const int bb = (mb << 3) + (prow2 >> 3);
      const int dd = (nb << 3) + (prow2 & 7);
      float v = acc2[ni2][qq] + outb[f];
      out[(size_t)((bb << 8) + dd) * 128 + f] = v / (1e-3f + nrm[(bb << 8) + dd]);
    }
  }
}

extern "C" void kernel_launch(void* const* d_in, const int* in_sizes, int n_in,
                              void* d_out, int out_size, void* d_ws, size_t ws_size,
                              hipStream_t stream) {
  const float* act = (const float*)d_in[0];
  const float* mask = (const float*)d_in[1];
  const float* lns = (const float*)d_in[2];
  const float* lno = (const float*)d_in[3];
  const float* lw = (const float*)d_in[4];
  const float* lb = (const float*)d_in[5];
  const float* rw = (const float*)d_in[6];
  const float* rbv = (const float*)d_in[7];
  const float* ow = (const float*)d_in[8];
  const float* ob = (const float*)d_in[9];
  float* out = (float*)d_out;
  char* ws = (char*)d_ws;

  unsigned short* Lt = (unsigned short*)(ws);               // 8192*512 bf16 = 8 MB
  unsigned short* Rt = (unsigned short*)(ws + 8388608);     // 8 MB
  unsigned short* Wt = (unsigned short*)(ws + 16777216);    // 128*1024 bf16 = 256 KB
  unsigned short* wcombT = (unsigned short*)(ws + 17039360);// 64*256 bf16 = 32 KB
  float* nrm = (float*)(ws + 17072128);                     // 256*256 f32 = 256 KB

  hipLaunchKernelGGL(prep_k, dim3(512), dim3(256), 0, stream, lw, rw, ow, Wt, wcombT);
  hipLaunchKernelGGL(norm_k, dim3(256), dim3(256), 0, stream, mask, nrm);
  hipLaunchKernelGGL(ln_proj, dim3(8, 256), dim3(256), 0, stream,
                     act, mask, lns, lno, lb, rbv, wcombT, Lt, Rt);
  hipLaunchKernelGGL(gemm_fused, dim3(1024), dim3(512), 0, stream,
                     Lt, Rt, Wt, nrm, ob, out);
}

// Round 3
// 188.329 us; speedup vs baseline: 1.7511x; 1.4308x over previous
//
#include <hip/hip_runtime.h>
#include <hip/hip_bf16.h>
#include <stdint.h>

typedef short bf16x8 __attribute__((ext_vector_type(8)));
typedef float f32x4 __attribute__((ext_vector_type(4)));
typedef unsigned short u16x4 __attribute__((ext_vector_type(4)));
typedef unsigned short u16x8 __attribute__((ext_vector_type(8)));

#define GLOAD16(g, l) __builtin_amdgcn_global_load_lds( \
    (const __attribute__((address_space(1))) void*)(g), \
    (__attribute__((address_space(3))) void*)(l), 16, 0, 0)

__device__ __forceinline__ unsigned short f2bf(float f) {
  unsigned u = __float_as_uint(f);
  unsigned r = (u + 0x7fffu + ((u >> 16) & 1u)) >> 16;
  return (unsigned short)r;
}

// ---------------- prep: Wt[f][k2'] bf16 with k2' = e*32 + c ; wcombT[c][m] bf16
__global__ __launch_bounds__(256) void prep_k(
    const float* __restrict__ lw, const float* __restrict__ rw,
    const float* __restrict__ ow, unsigned short* __restrict__ Wt,
    unsigned short* __restrict__ wcombT) {
  int idx = blockIdx.x * 256 + threadIdx.x;
  if (idx < 131072) {
    int f = idx >> 10, k2 = idx & 1023;
    int e = k2 >> 5, c = k2 & 31;
    Wt[idx] = f2bf(ow[(size_t)((c << 5) + e) * 128 + f]);
  }
  if (idx < 16384) {
    int c = idx >> 8, m = idx & 255;
    wcombT[idx] = f2bf(c < 32 ? lw[m * 32 + c] : rw[m * 32 + (c - 32)]);
  }
}

// ---------------- norm[b][d] = sum_a mask[a,b]*mask[a,d]
__global__ __launch_bounds__(256) void norm_k(const float* __restrict__ mask,
                                              float* __restrict__ nrm) {
  int b = blockIdx.x, d = threadIdx.x;
  float s = 0.f;
  for (int a = 0; a < 512; ++a)
    s += mask[a * 256 + b] * mask[a * 256 + d];
  nrm[(b << 8) + d] = s;
}

// ---------------- fused LayerNorm + projections via MFMA (unchanged from R2)
__global__ __launch_bounds__(256) void ln_proj(
    const float* __restrict__ act, const float* __restrict__ mask,
    const float* __restrict__ lns, const float* __restrict__ lno,
    const float* __restrict__ lb, const float* __restrict__ rb,
    const unsigned short* __restrict__ wcombT,
    unsigned short* __restrict__ Lt, unsigned short* __restrict__ Rt) {
  __shared__ char smem[65536];  // A 32KB | B 32KB
  const int tid = threadIdx.x;
  const int lane = tid & 63;
  const int w = tid >> 6;
  const int b = blockIdx.y;
  const int a0 = blockIdx.x << 6;
  const int r = tid >> 2;
  const int q = tid & 3;

  f32x4 xv[16];
  const float* src = act + ((size_t)(a0 + r) * 256 + b) * 256 + (q << 6);
  #pragma unroll
  for (int i = 0; i < 16; ++i) xv[i] = *(const f32x4*)(src + (i << 2));
  float s = 0.f, sq = 0.f;
  #pragma unroll
  for (int i = 0; i < 16; ++i) {
    f32x4 v = xv[i];
    s += v[0] + v[1] + v[2] + v[3];
    sq += v[0] * v[0] + v[1] * v[1] + v[2] * v[2] + v[3] * v[3];
  }
  s += __shfl_xor(s, 1); sq += __shfl_xor(sq, 1);
  s += __shfl_xor(s, 2); sq += __shfl_xor(sq, 2);
  const float mu = s * (1.f / 256.f);
  const float rs = rsqrtf(sq * (1.f / 256.f) - mu * mu + 1e-5f);

  {
    const unsigned short* wsrc = wcombT + r * 256 + (q << 6);
    #pragma unroll
    for (int i = 0; i < 8; ++i) {
      u16x8 v = *(const u16x8*)(wsrc + (i << 3));
      const int c = (q << 3) + i;
      *(u16x8*)(smem + 32768 + (r << 9) + ((c ^ (r & 7)) << 4)) = v;
    }
  }
  #pragma unroll
  for (int i = 0; i < 8; ++i) {
    u16x8 pk;
    #pragma unroll
    for (int h = 0; h < 2; ++h) {
      const int b4 = (i << 1) + h;
      const f32x4 sc = *(const f32x4*)(lns + (q << 6) + (b4 << 2));
      const f32x4 of = *(const f32x4*)(lno + (q << 6) + (b4 << 2));
      const f32x4 v = xv[b4];
      #pragma unroll
      for (int jj = 0; jj < 4; ++jj)
        pk[(h << 2) + jj] = f2bf((v[jj] - mu) * rs * sc[jj] + of[jj]);
    }
    const int c = (q << 3) + i;
    *(u16x8*)(smem + (r << 9) + ((c ^ (r & 7)) << 4)) = pk;
  }
  __syncthreads();

  const int wr = w >> 1, wc = w & 1;
  const int mrow = lane & 15, g = lane >> 4;
  f32x4 acc[2][2];
  #pragma unroll
  for (int i = 0; i < 2; ++i)
    #pragma unroll
    for (int jj = 0; jj < 2; ++jj) acc[i][jj] = (f32x4){0.f, 0.f, 0.f, 0.f};
  #pragma unroll
  for (int kk = 0; kk < 8; ++kk) {
    bf16x8 af[2], bfr[2];
    #pragma unroll
    for (int mi = 0; mi < 2; ++mi) {
      const int row = (wr << 5) + (mi << 4) + mrow;
      af[mi] = *(const bf16x8*)(smem + (row << 9) + ((((kk << 2) + g) ^ (row & 7)) << 4));
    }
    #pragma unroll
    for (int ni = 0; ni < 2; ++ni) {
      const int row = (wc << 5) + (ni << 4) + mrow;
      bfr[ni] = *(const bf16x8*)(smem + 32768 + (row << 9) + ((((kk << 2) + g) ^ (row & 7)) << 4));
    }
    #pragma unroll
    for (int mi = 0; mi < 2; ++mi)
      #pragma unroll
      for (int ni = 0; ni < 2; ++ni)
        acc[mi][ni] = __builtin_amdgcn_mfma_f32_16x16x32_bf16(af[mi], bfr[ni], acc[mi][ni], 0, 0, 0);
  }

  #pragma unroll
  for (int ni = 0; ni < 2; ++ni) {
    const int c31 = (ni << 4) + mrow;
    const float bias = (wc == 0) ? lb[c31] : rb[c31];
    unsigned short* dst = (wc == 0) ? Lt : Rt;
    #pragma unroll
    for (int mi = 0; mi < 2; ++mi) {
      u16x4 pk;
      #pragma unroll
      for (int qq = 0; qq < 4; ++qq) {
        const int ar = (wr << 5) + (mi << 4) + (g << 2) + qq;
        const float mk = mask[(size_t)(a0 + ar) * 256 + b];
        pk[qq] = f2bf((acc[mi][ni][qq] + bias) * mk);
      }
      *(u16x4*)(dst + (size_t)(b * 32 + c31) * 512 + a0 + (wr << 5) + (mi << 4) + (g << 2)) = pk;
    }
  }
}

// ---------------- main GEMM: 256x256 tile, 8 waves, BK=64, 8-phase counted-vmcnt
// schedule (4 phases per K-tile, 2 K-tiles per 8 phases). Fused epilogue:
// op tile -> opvec[64][1024] bf16 (LDS reuse, dual-XOR swz) -> x Wt -> out.
__global__ __launch_bounds__(512, 2) void gemm_fused(
    const unsigned short* __restrict__ Lt, const unsigned short* __restrict__ Rt,
    const unsigned short* __restrict__ Wt, const float* __restrict__ nrm,
    const float* __restrict__ outb, float* __restrict__ out) {
  __shared__ char smem[131072];  // dbuf 2x64KB (A 32KB | B 32KB); reused as opvec
  const int tid = threadIdx.x;
  const int lane = tid & 63;
  const int w = tid >> 6;              // 0..7
  const int wr = w >> 2, wc = w & 3;   // 2 x 4 wave grid; wave owns 128m x 64n
  const int mrow = lane & 15, g = lane >> 4;

  // XCD mapping with L2-octet order: each XCD walks 8mb x 4nb sub-blocks
  // (3 MB working set < 4 MB L2); 32 concurrent blocks/XCD = one octet.
  const int bid = blockIdx.x;
  const int xcd = bid & 7, j = bid >> 3;
  const int mb = ((j >> 5) << 3) | (j & 7);
  const int nb = (xcd << 2) | ((j >> 3) & 3);
  const int m0i = mb << 8, n0i = nb << 8;

  const int srow = lane >> 3;
  const int scol = ((lane & 7) ^ srow) << 3;  // pre-swizzled source k offset

  f32x4 acc[8][4];
  #pragma unroll
  for (int i = 0; i < 8; ++i)
    #pragma unroll
    for (int jj = 0; jj < 4; ++jj) acc[i][jj] = (f32x4){0.f, 0.f, 0.f, 0.f};

  // prologue: stage K-tile 0, issue order B0,B1,A-r0s,A-r1s (8 loads/thread-pairs)
  {
    auto STG0 = [&](const unsigned short* gsrc, int growbase, int dstoff) {
      GLOAD16(gsrc + ((size_t)(growbase + (w << 3) + srow) << 9) + scol,
              smem + dstoff + (w << 10) + (lane << 4));
    };
    STG0(Rt, n0i, 32768);       STG0(Rt, n0i + 64, 40960);
    STG0(Rt, n0i + 128, 49152); STG0(Rt, n0i + 192, 57344);
    STG0(Lt, m0i, 0);           STG0(Lt, m0i + 128, 16384);
    STG0(Lt, m0i + 64, 8192);   STG0(Lt, m0i + 192, 24576);
  }
  asm volatile("s_waitcnt vmcnt(2)" ::: "memory");  // B+A-r0 of tile 0 landed
  __builtin_amdgcn_s_barrier();

  #pragma unroll 1
  for (int t = 0; t < 8; ++t) {
    const char* bufp = smem + ((t & 1) << 16);
    const int nbuf = ((t + 1) & 1) << 16;
    const int k1 = (t + 1) << 6;
    const bool pf = (t < 7);
    auto STG = [&](const unsigned short* gsrc, int growbase, int dstoff) {
      GLOAD16(gsrc + ((size_t)(growbase + (w << 3) + srow) << 9) + k1 + scol,
              smem + nbuf + dstoff + (w << 10) + (lane << 4));
    };
    bf16x8 bfr[4][2];
    #pragma unroll
    for (int p = 0; p < 4; ++p) {
      // ds-read this phase's A quadrant (rows 32p..32p+31 of A-half(wr))
      bf16x8 af[2][2];
      #pragma unroll
      for (int mi_ = 0; mi_ < 2; ++mi_)
        #pragma unroll
        for (int kk = 0; kk < 2; ++kk) {
          const int row = (wr << 7) + (((p << 1) + mi_) << 4) + mrow;
          af[mi_][kk] = *(const bf16x8*)(bufp + (row << 7) + ((((kk << 2) + g) ^ (row & 7)) << 4));
        }
      if (p == 0) {  // all B frags once per K-tile (held in regs)
        #pragma unroll
        for (int ni = 0; ni < 4; ++ni)
          #pragma unroll
          for (int kk = 0; kk < 2; ++kk) {
            const int row = (wc << 6) + (ni << 4) + mrow;
            bfr[ni][kk] = *(const bf16x8*)(bufp + 32768 + (row << 7) + ((((kk << 2) + g) ^ (row & 7)) << 4));
          }
      }
      // prefetch one half-tile of K-tile t+1 per phase
      if (pf) {
        if (p == 0)      { STG(Rt, n0i, 32768);       STG(Rt, n0i + 64, 40960); }
        else if (p == 1) { STG(Rt, n0i + 128, 49152); STG(Rt, n0i + 192, 57344); }
        else if (p == 2) { STG(Lt, m0i, 0);           STG(Lt, m0i + 128, 16384); }
        else             { STG(Lt, m0i + 64, 8192);   STG(Lt, m0i + 192, 24576); }
      }
      __builtin_amdgcn_s_barrier();
      asm volatile("s_waitcnt lgkmcnt(0)" ::: "memory");
      __builtin_amdgcn_sched_barrier(0);
      __builtin_amdgcn_s_setprio(1);
      #pragma unroll
      for (int kk = 0; kk < 2; ++kk)
        #pragma unroll
        for (int mi_ = 0; mi_ < 2; ++mi_)
          #pragma unroll
          for (int ni = 0; ni < 4; ++ni)
            acc[(p << 1) + mi_][ni] = __builtin_amdgcn_mfma_f32_16x16x32_bf16(
                af[mi_][kk], bfr[ni][kk], acc[(p << 1) + mi_][ni], 0, 0, 0);
      __builtin_amdgcn_s_setprio(0);
      // counted vmcnt: ledger = 2 loads/phase, FIFO drain
      if (p == 1) {
        if (pf) asm volatile("s_waitcnt vmcnt(4)" ::: "memory");  // drains A-r1 of tile t
        else    asm volatile("s_waitcnt vmcnt(0)" ::: "memory");  // last tile
      } else if (p == 3 && pf) {
        asm volatile("s_waitcnt vmcnt(2)" ::: "memory");  // drains B+A-r0 of tile t+1
      }
      __builtin_amdgcn_s_barrier();
    }
  }

  // scatter op tile -> opvec[p][k2'] bf16, p = bloc*8+dloc, k2' = e*32+c, dual-XOR swz
  #pragma unroll
  for (int mi = 0; mi < 8; ++mi) {
    #pragma unroll
    for (int ni = 0; ni < 4; ++ni) {
      const int p = (((wr << 2) + (mi >> 1)) << 3) | ((wc << 1) + (ni >> 1));
      const int ow_ = ((ni & 1) << 10) + (mrow << 6) + ((mi & 1) << 5) + (g << 3);
      u16x4 pk;
      #pragma unroll
      for (int qq = 0; qq < 4; ++qq) pk[qq] = f2bf(acc[mi][ni][qq]);
      *(u16x4*)(smem + (p << 11) + (ow_ ^ ((p & 7) << 4) ^ (((ow_ >> 7) & 7) << 4))) = pk;
    }
  }
  __syncthreads();

  // stage 2: out2[p][f] = sum_k2' opvec[p][k2'] * Wt[f][k2']
  // wave owns a DISTINCT 16-f slice x all 64 p => Wt read exactly once per block
  const int f0 = w << 4;
  f32x4 acc2[4];
  #pragma unroll
  for (int i = 0; i < 4; ++i) acc2[i] = (f32x4){0.f, 0.f, 0.f, 0.f};
  const unsigned short* wrow = Wt + (size_t)(f0 + mrow) * 1024;
  #pragma unroll 4
  for (int kk2 = 0; kk2 < 32; ++kk2) {
    const bf16x8 b2 = *(const bf16x8*)(wrow + (kk2 << 5) + (g << 3));
    const int orr = (kk2 << 6) + (g << 4);
    #pragma unroll
    for (int pg = 0; pg < 4; ++pg) {
      const int prow = (pg << 4) + mrow;
      const bf16x8 a2 = *(const bf16x8*)(smem + (prow << 11) +
          (orr ^ ((prow & 7) << 4) ^ (((orr >> 7) & 7) << 4)));
      acc2[pg] = __builtin_amdgcn_mfma_f32_16x16x32_bf16(a2, b2, acc2[pg], 0, 0, 0);
    }
  }

  // epilogue: bias, /(eps+norm), store
  const float ob_ = outb[f0 + mrow];
  #pragma unroll
  for (int pg = 0; pg < 4; ++pg) {
    #pragma unroll
    for (int qq = 0; qq < 4; ++qq) {
      const int p = (pg << 4) + (g << 2) + qq;
      const int f = f0 + mrow;
      const int bb = (mb << 3) + (p >> 3);
      const int dd = (nb << 3) + (p & 7);
      const float v = acc2[pg][qq] + ob_;
      out[(size_t)((bb << 8) + dd) * 128 + f] = v / (1e-3f + nrm[(bb << 8) + dd]);
    }
  }
}

extern "C" void kernel_launch(void* const* d_in, const int* in_sizes, int n_in,
                              void* d_out, int out_size, void* d_ws, size_t ws_size,
                              hipStream_t stream) {
  const float* act = (const float*)d_in[0];
  const float* mask = (const float*)d_in[1];
  const float* lns = (const float*)d_in[2];
  const float* lno = (const float*)d_in[3];
  const float* lw = (const float*)d_in[4];
  const float* lb = (const float*)d_in[5];
  const float* rw = (const float*)d_in[6];
  const float* rbv = (const float*)d_in[7];
  const float* ow = (const float*)d_in[8];
  const float* ob = (const float*)d_in[9];
  float* out = (float*)d_out;
  char* ws = (char*)d_ws;

  unsigned short* Lt = (unsigned short*)(ws);               // 8192*512 bf16 = 8 MB
  unsigned short* Rt = (unsigned short*)(ws + 8388608);     // 8 MB
  unsigned short* Wt = (unsigned short*)(ws + 16777216);    // 128*1024 bf16 = 256 KB
  unsigned short* wcombT = (unsigned short*)(ws + 17039360);// 64*256 bf16 = 32 KB
  float* nrm = (float*)(ws + 17072128);                     // 256*256 f32 = 256 KB

  hipLaunchKernelGGL(prep_k, dim3(512), dim3(256), 0, stream, lw, rw, ow, Wt, wcombT);
  hipLaunchKernelGGL(norm_k, dim3(256), dim3(256), 0, stream, mask, nrm);
  hipLaunchKernelGGL(ln_proj, dim3(8, 256), dim3(256), 0, stream,
                     act, mask, lns, lno, lb, rbv, wcombT, Lt, Rt);
  hipLaunchKernelGGL(gemm_fused, dim3(1024), dim3(512), 0, stream,
                     Lt, Rt, Wt, nrm, ob, out);
}

// Round 4
// 185.631 us; speedup vs baseline: 1.7765x; 1.0145x over previous
//
#include <hip/hip_runtime.h>
#include <hip/hip_bf16.h>
#include <stdint.h>

typedef short bf16x8 __attribute__((ext_vector_type(8)));
typedef float f32x4 __attribute__((ext_vector_type(4)));
typedef unsigned short u16x4 __attribute__((ext_vector_type(4)));
typedef unsigned short u16x8 __attribute__((ext_vector_type(8)));

#define GLOAD16(g, l) __builtin_amdgcn_global_load_lds( \
    (const __attribute__((address_space(1))) void*)(g), \
    (__attribute__((address_space(3))) void*)(l), 16, 0, 0)

__device__ __forceinline__ unsigned short f2bf(float f) {
  unsigned u = __float_as_uint(f);
  unsigned r = (u + 0x7fffu + ((u >> 16) & 1u)) >> 16;
  return (unsigned short)r;
}

// ---------------- prep: Wt[f][k2'] bf16 (k2' = e*32+c); wfragG = projection
// weights pre-formatted in MFMA B-fragment order for ln_proj.
__global__ __launch_bounds__(256) void prep_k(
    const float* __restrict__ lw, const float* __restrict__ rw,
    const float* __restrict__ ow, unsigned short* __restrict__ Wt,
    unsigned short* __restrict__ wfragG) {
  int idx = blockIdx.x * 256 + threadIdx.x;
  if (idx < 131072) {
    int f = idx >> 10, k2 = idx & 1023;
    int e = k2 >> 5, c = k2 & 31;
    Wt[idx] = f2bf(ow[(size_t)((c << 5) + e) * 128 + f]);
  }
  if (idx < 16384) {
    // frag layout: idx = ((wc*2+ni)*8+kk)*512 + lane*8 + j
    int frag = idx >> 9, lane = (idx >> 3) & 63, j = idx & 7;
    int wc = frag >> 4, ni = (frag >> 3) & 1, kk = frag & 7;
    int mrow = lane & 15, g = lane >> 4;
    int c = wc * 32 + ni * 16 + mrow;   // 0..63 (c<32: left, else right)
    int k = kk * 32 + g * 8 + j;        // 0..255 (m index)
    wfragG[idx] = f2bf(c < 32 ? lw[k * 32 + c] : rw[k * 32 + (c - 32)]);
  }
}

// ---------------- norm[b][d] = sum_a mask[a,b]*mask[a,d]
__global__ __launch_bounds__(256) void norm_k(const float* __restrict__ mask,
                                              float* __restrict__ nrm) {
  int b = blockIdx.x, d = threadIdx.x;
  float s = 0.f;
  #pragma unroll 8
  for (int a = 0; a < 512; ++a)
    s += mask[a * 256 + b] * mask[a * 256 + d];
  nrm[(b << 8) + d] = s;
}

// ---------------- fused LayerNorm + projections via MFMA.
// B-frags come straight from wfragG (L2-resident) — no B staging, 32KB LDS.
__global__ __launch_bounds__(256) void ln_proj(
    const float* __restrict__ act, const float* __restrict__ mask,
    const float* __restrict__ lns, const float* __restrict__ lno,
    const float* __restrict__ lb, const float* __restrict__ rb,
    const unsigned short* __restrict__ wfragG,
    unsigned short* __restrict__ Lt, unsigned short* __restrict__ Rt) {
  __shared__ char smem[32768];  // A tile only
  const int tid = threadIdx.x;
  const int lane = tid & 63;
  const int w = tid >> 6;
  const int b = blockIdx.y;
  const int a0 = blockIdx.x << 6;
  const int r = tid >> 2;
  const int q = tid & 3;

  f32x4 xv[16];
  const float* src = act + ((size_t)(a0 + r) * 256 + b) * 256 + (q << 6);
  #pragma unroll
  for (int i = 0; i < 16; ++i) xv[i] = *(const f32x4*)(src + (i << 2));
  float s = 0.f, sq = 0.f;
  #pragma unroll
  for (int i = 0; i < 16; ++i) {
    f32x4 v = xv[i];
    s += v[0] + v[1] + v[2] + v[3];
    sq += v[0] * v[0] + v[1] * v[1] + v[2] * v[2] + v[3] * v[3];
  }
  s += __shfl_xor(s, 1); sq += __shfl_xor(sq, 1);
  s += __shfl_xor(s, 2); sq += __shfl_xor(sq, 2);
  const float mu = s * (1.f / 256.f);
  const float rs = rsqrtf(sq * (1.f / 256.f) - mu * mu + 1e-5f);

  // scale + convert + stage A tile, swizzled (row=r: 512B, 32 slots)
  #pragma unroll
  for (int i = 0; i < 8; ++i) {
    u16x8 pk;
    #pragma unroll
    for (int h = 0; h < 2; ++h) {
      const int b4 = (i << 1) + h;
      const f32x4 sc = *(const f32x4*)(lns + (q << 6) + (b4 << 2));
      const f32x4 of = *(const f32x4*)(lno + (q << 6) + (b4 << 2));
      const f32x4 v = xv[b4];
      #pragma unroll
      for (int jj = 0; jj < 4; ++jj)
        pk[(h << 2) + jj] = f2bf((v[jj] - mu) * rs * sc[jj] + of[jj]);
    }
    const int c = (q << 3) + i;
    *(u16x8*)(smem + (r << 9) + ((c ^ (r & 7)) << 4)) = pk;
  }
  __syncthreads();

  const int wr = w >> 1, wc = w & 1;
  const int mrow = lane & 15, g = lane >> 4;
  f32x4 acc[2][2];
  #pragma unroll
  for (int i = 0; i < 2; ++i)
    #pragma unroll
    for (int jj = 0; jj < 2; ++jj) acc[i][jj] = (f32x4){0.f, 0.f, 0.f, 0.f};
  #pragma unroll
  for (int kk = 0; kk < 8; ++kk) {
    bf16x8 af[2], bfr[2];
    #pragma unroll
    for (int mi = 0; mi < 2; ++mi) {
      const int row = (wr << 5) + (mi << 4) + mrow;
      af[mi] = *(const bf16x8*)(smem + (row << 9) + ((((kk << 2) + g) ^ (row & 7)) << 4));
    }
    #pragma unroll
    for (int ni = 0; ni < 2; ++ni)
      bfr[ni] = *(const bf16x8*)(wfragG + (size_t)((((wc << 1) + ni) << 3) + kk) * 512 + (lane << 3));
    #pragma unroll
    for (int mi = 0; mi < 2; ++mi)
      #pragma unroll
      for (int ni = 0; ni < 2; ++ni)
        acc[mi][ni] = __builtin_amdgcn_mfma_f32_16x16x32_bf16(af[mi], bfr[ni], acc[mi][ni], 0, 0, 0);
  }

  #pragma unroll
  for (int ni = 0; ni < 2; ++ni) {
    const int c31 = (ni << 4) + mrow;
    const float bias = (wc == 0) ? lb[c31] : rb[c31];
    unsigned short* dst = (wc == 0) ? Lt : Rt;
    #pragma unroll
    for (int mi = 0; mi < 2; ++mi) {
      u16x4 pk;
      #pragma unroll
      for (int qq = 0; qq < 4; ++qq) {
        const int ar = (wr << 5) + (mi << 4) + (g << 2) + qq;
        const float mk = mask[(size_t)(a0 + ar) * 256 + b];
        pk[qq] = f2bf((acc[mi][ni][qq] + bias) * mk);
      }
      *(u16x4*)(dst + (size_t)(b * 32 + c31) * 512 + a0 + (wr << 5) + (mi << 4) + (g << 2)) = pk;
    }
  }
}

// ---------------- main GEMM: 256x256 tile, 8 waves, BK=64.
// Deep-pipelined 4-phase/K-tile schedule: chunk = 8KB = 64 rows.
//   A-chunk p (per K-tile) = rows [32p,32p+32) U [128+32p,128+32p+32)  (the rows
//     phase p consumes for both wr halves);  B-chunk q = rows [64q, 64q+64).
// Issue (tile t): p0: A3(buf t+1); p1: B0,B1,B2(buf t+2); p2: B3,A0(buf t+2);
//   p3: A1,A2(buf t+2).  buf(t+2) = current read buffer, just-freed slots.
// Drains: p2: vmcnt(13) [lands A3(buf t), 6-phase slack]; p3: vmcnt(8)
//   [lands buf(t+1)'s 7, 3-6 phase slack]. Never vmcnt(0) in steady state.
__global__ __launch_bounds__(512, 2) void gemm_fused(
    const unsigned short* __restrict__ Lt, const unsigned short* __restrict__ Rt,
    const unsigned short* __restrict__ Wt, const float* __restrict__ nrm,
    const float* __restrict__ outb, float* __restrict__ out) {
  __shared__ char smem[131072];  // 2 bufs x (A 32KB | B 32KB); reused as opvec
  const int tid = threadIdx.x;
  const int lane = tid & 63;
  const int w = tid >> 6;
  const int wr = w >> 2, wc = w & 3;
  const int mrow = lane & 15, g = lane >> 4;

  // XCD mapping with L2-octet order (8mb x 4nb per XCD, ~3MB < 4MB L2)
  const int bid = blockIdx.x;
  const int xcd = bid & 7, jj_ = bid >> 3;
  const int mb = ((jj_ >> 5) << 3) | (jj_ & 7);
  const int nb = (xcd << 2) | ((jj_ >> 3) & 3);
  const int m0i = mb << 8, n0i = nb << 8;

  const int r_l = tid >> 3;                       // staging row-local 0..63
  const int scol = ((tid & 7) ^ (r_l & 7)) << 3;  // pre-swizzled source col (elems)
  const int arow_g = m0i + r_l + ((r_l & 32) ? 96 : 0);  // + 32p later

  f32x4 acc[8][4];
  #pragma unroll
  for (int i = 0; i < 8; ++i)
    #pragma unroll
    for (int jj = 0; jj < 4; ++jj) acc[i][jj] = (f32x4){0.f, 0.f, 0.f, 0.f};

  auto STGA = [&](int buf, int p, int kt) {
    GLOAD16(Lt + ((size_t)(arow_g + (p << 5)) << 9) + (kt << 6) + scol,
            smem + buf + (p << 13) + (tid << 4));
  };
  auto STGB = [&](int buf, int q, int kt) {
    GLOAD16(Rt + ((size_t)(n0i + (q << 6) + r_l) << 9) + (kt << 6) + scol,
            smem + buf + 32768 + (q << 13) + (tid << 4));
  };

  // prologue: buf0 all 8 chunks (kt=0), then buf1's first 7 (kt=1)
  #pragma unroll
  for (int p = 0; p < 4; ++p) STGA(0, p, 0);
  #pragma unroll
  for (int qd = 0; qd < 4; ++qd) STGB(0, qd, 0);
  #pragma unroll
  for (int qd = 0; qd < 4; ++qd) STGB(65536, qd, 1);
  STGA(65536, 0, 1); STGA(65536, 1, 1); STGA(65536, 2, 1);
  asm volatile("s_waitcnt vmcnt(7)" ::: "memory");  // buf0 landed
  __builtin_amdgcn_s_barrier();

  #pragma unroll 1
  for (int t = 0; t < 8; ++t) {
    const int cbuf = (t & 1) << 16;        // read buf; also stage target for buf(t+2)
    const int nbuf = ((t + 1) & 1) << 16;  // buf(t+1)
    bf16x8 bfr[4][2];
    #pragma unroll
    for (int p = 0; p < 4; ++p) {
      // ds-read this phase's A frags (chunk p)
      bf16x8 af[2][2];
      #pragma unroll
      for (int mi_ = 0; mi_ < 2; ++mi_)
        #pragma unroll
        for (int kk = 0; kk < 2; ++kk) {
          const int loc = (wr << 5) + (mi_ << 4) + mrow;
          af[mi_][kk] = *(const bf16x8*)(smem + cbuf + (p << 13) + (loc << 7) +
                                         ((((kk << 2) + g) ^ (mrow & 7)) << 4));
        }
      if (p == 0) {  // all B frags once per K-tile (chunk wc)
        #pragma unroll
        for (int ni = 0; ni < 4; ++ni)
          #pragma unroll
          for (int kk = 0; kk < 2; ++kk) {
            const int loc = (ni << 4) + mrow;
            bfr[ni][kk] = *(const bf16x8*)(smem + cbuf + 32768 + (wc << 13) + (loc << 7) +
                                           ((((kk << 2) + g) ^ (mrow & 7)) << 4));
          }
      }
      // staged issues (see ledger in header comment)
      if (p == 0) { if (t < 7) STGA(nbuf, 3, t + 1); }
      else if (p == 1) { if (t < 6) { STGB(cbuf, 0, t + 2); STGB(cbuf, 1, t + 2); STGB(cbuf, 2, t + 2); } }
      else if (p == 2) { if (t < 6) { STGB(cbuf, 3, t + 2); STGA(cbuf, 0, t + 2); } }
      else { if (t < 6) { STGA(cbuf, 1, t + 2); STGA(cbuf, 2, t + 2); } }

      __builtin_amdgcn_s_barrier();
      asm volatile("s_waitcnt lgkmcnt(0)" ::: "memory");
      __builtin_amdgcn_sched_barrier(0);
      __builtin_amdgcn_s_setprio(1);
      #pragma unroll
      for (int kk = 0; kk < 2; ++kk)
        #pragma unroll
        for (int mi_ = 0; mi_ < 2; ++mi_)
          #pragma unroll
          for (int ni = 0; ni < 4; ++ni)
            acc[(p << 1) + mi_][ni] = __builtin_amdgcn_mfma_f32_16x16x32_bf16(
                af[mi_][kk], bfr[ni][kk], acc[(p << 1) + mi_][ni], 0, 0, 0);
      __builtin_amdgcn_s_setprio(0);
      if (p == 2) {
        if (t < 6)      asm volatile("s_waitcnt vmcnt(13)" ::: "memory");
        else if (t == 6) asm volatile("s_waitcnt vmcnt(8)" ::: "memory");
        else            asm volatile("s_waitcnt vmcnt(0)" ::: "memory");
      } else if (p == 3) {
        if (t < 6)      asm volatile("s_waitcnt vmcnt(8)" ::: "memory");
        else if (t == 6) asm volatile("s_waitcnt vmcnt(1)" ::: "memory");
      }
      __builtin_amdgcn_s_barrier();
    }
  }

  // scatter op tile -> opvec[p][k2'] bf16, p = bloc*8+dloc, k2' = e*32+c, dual-XOR swz
  #pragma unroll
  for (int mi = 0; mi < 8; ++mi) {
    #pragma unroll
    for (int ni = 0; ni < 4; ++ni) {
      const int p = (((wr << 2) + (mi >> 1)) << 3) | ((wc << 1) + (ni >> 1));
      const int ow_ = ((ni & 1) << 10) + (mrow << 6) + ((mi & 1) << 5) + (g << 3);
      u16x4 pk;
      #pragma unroll
      for (int qq = 0; qq < 4; ++qq) pk[qq] = f2bf(acc[mi][ni][qq]);
      *(u16x4*)(smem + (p << 11) + (ow_ ^ ((p & 7) << 4) ^ (((ow_ >> 7) & 7) << 4))) = pk;
    }
  }
  __syncthreads();

  // stage 2: out2[p][f] = sum_k2' opvec[p][k2'] * Wt[f][k2']; wave owns 16 f x 64 p
  const int f0 = w << 4;
  f32x4 acc2[4];
  #pragma unroll
  for (int i = 0; i < 4; ++i) acc2[i] = (f32x4){0.f, 0.f, 0.f, 0.f};
  const unsigned short* wrow = Wt + (size_t)(f0 + mrow) * 1024;
  #pragma unroll 4
  for (int kk2 = 0; kk2 < 32; ++kk2) {
    const bf16x8 b2 = *(const bf16x8*)(wrow + (kk2 << 5) + (g << 3));
    const int orr = (kk2 << 6) + (g << 4);
    #pragma unroll
    for (int pg = 0; pg < 4; ++pg) {
      const int prow = (pg << 4) + mrow;
      const bf16x8 a2 = *(const bf16x8*)(smem + (prow << 11) +
          (orr ^ ((prow & 7) << 4) ^ (((orr >> 7) & 7) << 4)));
      acc2[pg] = __builtin_amdgcn_mfma_f32_16x16x32_bf16(a2, b2, acc2[pg], 0, 0, 0);
    }
  }

  // epilogue: bias, /(eps+norm), store
  const float ob_ = outb[f0 + mrow];
  #pragma unroll
  for (int pg = 0; pg < 4; ++pg) {
    #pragma unroll
    for (int qq = 0; qq < 4; ++qq) {
      const int p = (pg << 4) + (g << 2) + qq;
      const int f = f0 + mrow;
      const int bb = (mb << 3) + (p >> 3);
      const int dd = (nb << 3) + (p & 7);
      const float v = acc2[pg][qq] + ob_;
      out[(size_t)((bb << 8) + dd) * 128 + f] = v / (1e-3f + nrm[(bb << 8) + dd]);
    }
  }
}

extern "C" void kernel_launch(void* const* d_in, const int* in_sizes, int n_in,
                              void* d_out, int out_size, void* d_ws, size_t ws_size,
                              hipStream_t stream) {
  const float* act = (const float*)d_in[0];
  const float* mask = (const float*)d_in[1];
  const float* lns = (const float*)d_in[2];
  const float* lno = (const float*)d_in[3];
  const float* lw = (const float*)d_in[4];
  const float* lb = (const float*)d_in[5];
  const float* rw = (const float*)d_in[6];
  const float* rbv = (const float*)d_in[7];
  const float* ow = (const float*)d_in[8];
  const float* ob = (const float*)d_in[9];
  float* out = (float*)d_out;
  char* ws = (char*)d_ws;

  unsigned short* Lt = (unsigned short*)(ws);               // 8192*512 bf16 = 8 MB
  unsigned short* Rt = (unsigned short*)(ws + 8388608);     // 8 MB
  unsigned short* Wt = (unsigned short*)(ws + 16777216);    // 128*1024 bf16 = 256 KB
  unsigned short* wfragG = (unsigned short*)(ws + 17039360);// 32*512 bf16 = 32 KB
  float* nrm = (float*)(ws + 17072128);                     // 256*256 f32 = 256 KB

  hipLaunchKernelGGL(prep_k, dim3(512), dim3(256), 0, stream, lw, rw, ow, Wt, wfragG);
  hipLaunchKernelGGL(norm_k, dim3(256), dim3(256), 0, stream, mask, nrm);
  hipLaunchKernelGGL(ln_proj, dim3(8, 256), dim3(256), 0, stream,
                     act, mask, lns, lno, lb, rbv, wfragG, Lt, Rt);
  hipLaunchKernelGGL(gemm_fused, dim3(1024), dim3(512), 0, stream,
                     Lt, Rt, Wt, nrm, ob, out);
}

// Round 5
// 158.616 us; speedup vs baseline: 2.0791x; 1.1703x over previous
//
#include <hip/hip_runtime.h>
#include <hip/hip_bf16.h>
#include <stdint.h>

typedef short bf16x8 __attribute__((ext_vector_type(8)));
typedef float f32x4 __attribute__((ext_vector_type(4)));
typedef unsigned short u16x4 __attribute__((ext_vector_type(4)));
typedef unsigned short u16x8 __attribute__((ext_vector_type(8)));

#define GLOAD16(g, l) __builtin_amdgcn_global_load_lds( \
    (const __attribute__((address_space(1))) void*)(g), \
    (__attribute__((address_space(3))) void*)(l), 16, 0, 0)

__device__ __forceinline__ unsigned short f2bf(float f) {
  unsigned u = __float_as_uint(f);
  unsigned r = (u + 0x7fffu + ((u >> 16) & 1u)) >> 16;
  return (unsigned short)r;
}

// ---------------- prep: Wt[f][k2'] bf16 (k2' = e*32+c); wfragG = projection
// weights pre-formatted in MFMA B-fragment order for ln_proj.
__global__ __launch_bounds__(256) void prep_k(
    const float* __restrict__ lw, const float* __restrict__ rw,
    const float* __restrict__ ow, unsigned short* __restrict__ Wt,
    unsigned short* __restrict__ wfragG) {
  int idx = blockIdx.x * 256 + threadIdx.x;
  if (idx < 131072) {
    int f = idx >> 10, k2 = idx & 1023;
    int e = k2 >> 5, c = k2 & 31;
    Wt[idx] = f2bf(ow[(size_t)((c << 5) + e) * 128 + f]);
  }
  if (idx < 16384) {
    int frag = idx >> 9, lane = (idx >> 3) & 63, j = idx & 7;
    int wc = frag >> 4, ni = (frag >> 3) & 1, kk = frag & 7;
    int mrow = lane & 15, g = lane >> 4;
    int c = wc * 32 + ni * 16 + mrow;
    int k = kk * 32 + g * 8 + j;
    wfragG[idx] = f2bf(c < 32 ? lw[k * 32 + c] : rw[k * 32 + (c - 32)]);
  }
}

// ---------------- norm[b][d] = sum_a mask[a,b]*mask[a,d]
__global__ __launch_bounds__(256) void norm_k(const float* __restrict__ mask,
                                              float* __restrict__ nrm) {
  int b = blockIdx.x, d = threadIdx.x;
  float s = 0.f;
  #pragma unroll 8
  for (int a = 0; a < 512; ++a)
    s += mask[a * 256 + b] * mask[a * 256 + d];
  nrm[(b << 8) + d] = s;
}

// ---------------- fused LayerNorm + projections via MFMA.
// Coalesced reads (16 lanes per row, 256B segments), per-row shfl stats,
// MFMA vs wfragG (L2-hot), LDS-transpose epilogue for 128B-contiguous stores.
__global__ __launch_bounds__(256, 4) void ln_proj(
    const float* __restrict__ act, const float* __restrict__ mask,
    const float* __restrict__ lns, const float* __restrict__ lno,
    const float* __restrict__ lb, const float* __restrict__ rb,
    const unsigned short* __restrict__ wfragG,
    unsigned short* __restrict__ Lt, unsigned short* __restrict__ Rt) {
  __shared__ char smem[32768];  // A tile [64 rows][512B swz]; reused as [64c][64a]
  const int tid = threadIdx.x;
  const int lane = tid & 63;
  const int w = tid >> 6;
  const int b = blockIdx.y;
  const int a0 = blockIdx.x << 6;
  const int l = tid & 15;   // lane within row-group
  const int rg = tid >> 4;  // row-group 0..15

  // LN params for this lane's 16-col slice
  f32x4 sc[4], of[4];
  #pragma unroll
  for (int j = 0; j < 4; ++j) {
    sc[j] = *(const f32x4*)(lns + (l << 4) + (j << 2));
    of[j] = *(const f32x4*)(lno + (l << 4) + (j << 2));
  }

  #pragma unroll
  for (int i = 0; i < 4; ++i) {
    const int r = rg + (i << 4);
    const float* src = act + ((size_t)(a0 + r) * 256 + b) * 256 + (l << 4);
    f32x4 xv[4];
    #pragma unroll
    for (int j = 0; j < 4; ++j) xv[j] = *(const f32x4*)(src + (j << 2));
    float s = 0.f, sq = 0.f;
    #pragma unroll
    for (int j = 0; j < 4; ++j) {
      f32x4 v = xv[j];
      s += v[0] + v[1] + v[2] + v[3];
      sq += v[0] * v[0] + v[1] * v[1] + v[2] * v[2] + v[3] * v[3];
    }
    s += __shfl_xor(s, 1); sq += __shfl_xor(sq, 1);
    s += __shfl_xor(s, 2); sq += __shfl_xor(sq, 2);
    s += __shfl_xor(s, 4); sq += __shfl_xor(sq, 4);
    s += __shfl_xor(s, 8); sq += __shfl_xor(sq, 8);
    const float mu = s * (1.f / 256.f);
    const float rs = rsqrtf(sq * (1.f / 256.f) - mu * mu + 1e-5f);
    #pragma unroll
    for (int hh = 0; hh < 2; ++hh) {
      u16x8 pk;
      #pragma unroll
      for (int j2 = 0; j2 < 2; ++j2) {
        const int j = (hh << 1) + j2;
        #pragma unroll
        for (int e = 0; e < 4; ++e)
          pk[(j2 << 2) + e] = f2bf((xv[j][e] - mu) * rs * sc[j][e] + of[j][e]);
      }
      const int c = (l << 1) + hh;  // 16B slot 0..31
      *(u16x8*)(smem + (r << 9) + ((c ^ (r & 7)) << 4)) = pk;
    }
  }
  __syncthreads();

  // MFMA 64x64x256: wave (wr, wc) owns 32 a x 32 c
  const int wr = w >> 1, wc = w & 1;
  const int mrow = lane & 15, g = lane >> 4;
  f32x4 acc[2][2];
  #pragma unroll
  for (int i = 0; i < 2; ++i)
    #pragma unroll
    for (int jj = 0; jj < 2; ++jj) acc[i][jj] = (f32x4){0.f, 0.f, 0.f, 0.f};
  #pragma unroll
  for (int kk = 0; kk < 8; ++kk) {
    bf16x8 af[2], bfr[2];
    #pragma unroll
    for (int mi = 0; mi < 2; ++mi) {
      const int row = (wr << 5) + (mi << 4) + mrow;
      af[mi] = *(const bf16x8*)(smem + (row << 9) + ((((kk << 2) + g) ^ (row & 7)) << 4));
    }
    #pragma unroll
    for (int ni = 0; ni < 2; ++ni)
      bfr[ni] = *(const bf16x8*)(wfragG + (size_t)((((wc << 1) + ni) << 3) + kk) * 512 + (lane << 3));
    #pragma unroll
    for (int mi = 0; mi < 2; ++mi)
      #pragma unroll
      for (int ni = 0; ni < 2; ++ni)
        acc[mi][ni] = __builtin_amdgcn_mfma_f32_16x16x32_bf16(af[mi], bfr[ni], acc[mi][ni], 0, 0, 0);
  }
  __syncthreads();

  // scatter (bias+mask applied) -> smem as [c64][a64] bf16, XOR-swizzled
  #pragma unroll
  for (int ni = 0; ni < 2; ++ni) {
    const int c = (wc << 5) + (ni << 4) + mrow;
    const float bias = (wc == 0) ? lb[(ni << 4) + mrow] : rb[(ni << 4) + mrow];
    #pragma unroll
    for (int mi = 0; mi < 2; ++mi) {
      const int aB = (wr << 5) + (mi << 4) + (g << 2);
      u16x4 pk;
      #pragma unroll
      for (int qq = 0; qq < 4; ++qq) {
        const float mk = mask[(size_t)(a0 + aB + qq) * 256 + b];
        pk[qq] = f2bf((acc[mi][ni][qq] + bias) * mk);
      }
      *(u16x4*)(smem + (c << 7) + ((((aB >> 3) & 7) ^ (c & 7)) << 4) + ((aB & 7) << 1)) = pk;
    }
  }
  __syncthreads();

  // coalesced store: 8 c-rows x 128B per instr
  #pragma unroll
  for (int s = 0; s < 2; ++s) {
    const int c = (w << 4) + (s << 3) + (lane >> 3);
    const int gr = lane & 7;
    const u16x8 v = *(const u16x8*)(smem + (c << 7) + ((gr ^ (c & 7)) << 4));
    unsigned short* dst = (c < 32) ? Lt : Rt;
    *(u16x8*)(dst + (size_t)(b * 32 + (c & 31)) * 512 + a0 + (gr << 3)) = v;
  }
}

// ---------------- main GEMM: 256x256 tile, 8 waves, BK=64, 4 phases/K-tile,
// ONE barrier per phase. Phase p = (h=p>>1, kk=p&1): reads A chunk (wr*2+h)
// frags for kk + (p<2: all B frags for kk). Staging 2 chunks/phase into
// buf(t+1); drains vmcnt(4)@p1, vmcnt(2)@p3 (FIFO ledger, never 0 steady).
// Fused epilogue: op tile -> opvec[64][1024] bf16 (LDS reuse) -> x Wt -> out.
__global__ __launch_bounds__(512, 2) void gemm_fused(
    const unsigned short* __restrict__ Lt, const unsigned short* __restrict__ Rt,
    const unsigned short* __restrict__ Wt, const float* __restrict__ nrm,
    const float* __restrict__ outb, float* __restrict__ out) {
  __shared__ char smem[131072];  // 2 bufs x (A 32KB | B 32KB); reused as opvec
  const int tid = threadIdx.x;
  const int lane = tid & 63;
  const int w = tid >> 6;
  const int wr = w >> 2, wc = w & 3;
  const int mrow = lane & 15, g = lane >> 4;

  // XCD mapping with L2-octet order (8mb x 4nb per XCD)
  const int bid = blockIdx.x;
  const int xcd = bid & 7, jj_ = bid >> 3;
  const int mb = ((jj_ >> 5) << 3) | (jj_ & 7);
  const int nb = (xcd << 2) | ((jj_ >> 3) & 3);
  const int m0i = mb << 8, n0i = nb << 8;

  const int scol = (((tid & 7) ^ ((tid >> 3) & 7)) << 3);  // pre-swz source col

  f32x4 acc[8][4];
  #pragma unroll
  for (int i = 0; i < 8; ++i)
    #pragma unroll
    for (int jj = 0; jj < 4; ++jj) acc[i][jj] = (f32x4){0.f, 0.f, 0.f, 0.f};

  // STG: one 8KB chunk (64 rows x 128B), linear LDS dest, pre-swz source
  auto STG = [&](const unsigned short* gsrc, int baserow, int dstoff, int kt) {
    GLOAD16(gsrc + ((size_t)(baserow + (tid >> 3)) << 9) + (kt << 6) + scol,
            smem + dstoff + (tid << 4));
  };

  // prologue: buf0, issue order B0..B3, A0, A2, A1, A3
  STG(Rt, n0i, 32768, 0);        STG(Rt, n0i + 64, 40960, 0);
  STG(Rt, n0i + 128, 49152, 0);  STG(Rt, n0i + 192, 57344, 0);
  STG(Lt, m0i, 0, 0);            STG(Lt, m0i + 128, 16384, 0);
  STG(Lt, m0i + 64, 8192, 0);    STG(Lt, m0i + 192, 24576, 0);
  asm volatile("s_waitcnt vmcnt(2)" ::: "memory");  // B0-3 + A0,A2 landed
  __builtin_amdgcn_s_barrier();

  #pragma unroll 1
  for (int t = 0; t < 8; ++t) {
    const int cbuf = (t & 1) << 16;
    const int nbuf = ((t + 1) & 1) << 16;
    const int k1 = t + 1;
    const bool pfe = (t < 7);
    bf16x8 bfr[4][2];
    #pragma unroll
    for (int p = 0; p < 4; ++p) {
      const int h = p >> 1, kk = p & 1;
      // ds-read A frags: chunk (wr*2+h), slot group kk
      bf16x8 af[4];
      #pragma unroll
      for (int mi_ = 0; mi_ < 4; ++mi_) {
        af[mi_] = *(const bf16x8*)(smem + cbuf + (((wr << 1) + h) << 13) +
                                   (((mi_ << 4) + mrow) << 7) +
                                   ((((kk << 2) + g) ^ (mrow & 7)) << 4));
      }
      if (p < 2) {  // B frags for kk=p (chunk wc), held in regs for h=1 phases
        #pragma unroll
        for (int ni = 0; ni < 4; ++ni)
          bfr[ni][p] = *(const bf16x8*)(smem + cbuf + 32768 + (wc << 13) +
                                        (((ni << 4) + mrow) << 7) +
                                        ((((p << 2) + g) ^ (mrow & 7)) << 4));
      }
      // staging: 2 chunks of buf(t+1) per phase
      if (pfe) {
        if (p == 0)      { STG(Rt, n0i, nbuf + 32768, k1);       STG(Rt, n0i + 64, nbuf + 40960, k1); }
        else if (p == 1) { STG(Rt, n0i + 128, nbuf + 49152, k1); STG(Rt, n0i + 192, nbuf + 57344, k1); }
        else if (p == 2) { STG(Lt, m0i, nbuf, k1);               STG(Lt, m0i + 128, nbuf + 16384, k1); }
        else             { STG(Lt, m0i + 64, nbuf + 8192, k1);   STG(Lt, m0i + 192, nbuf + 24576, k1); }
      }
      asm volatile("s_waitcnt lgkmcnt(0)" ::: "memory");
      __builtin_amdgcn_sched_barrier(0);
      __builtin_amdgcn_s_setprio(1);
      #pragma unroll
      for (int mi_ = 0; mi_ < 4; ++mi_)
        #pragma unroll
        for (int ni = 0; ni < 4; ++ni)
          acc[(h << 2) + mi_][ni] = __builtin_amdgcn_mfma_f32_16x16x32_bf16(
              af[mi_], bfr[ni][kk], acc[(h << 2) + mi_][ni], 0, 0, 0);
      __builtin_amdgcn_s_setprio(0);
      // counted drains (FIFO): issued/tile = [B0,B1, B2,B3, A0,A2, A1,A3]
      if (p == 1) {
        if (t < 7) asm volatile("s_waitcnt vmcnt(4)" ::: "memory");  // prev A1,A3
        else       asm volatile("s_waitcnt vmcnt(0)" ::: "memory");
      } else if (p == 3 && pfe) {
        asm volatile("s_waitcnt vmcnt(2)" ::: "memory");  // B0-3,A0,A2 of t+1
      }
      __builtin_amdgcn_s_barrier();
    }
  }

  // scatter op tile -> opvec[p][k2'] bf16, p = bloc*8+dloc, k2' = e*32+c, dual-XOR swz
  #pragma unroll
  for (int mi = 0; mi < 8; ++mi) {
    #pragma unroll
    for (int ni = 0; ni < 4; ++ni) {
      const int p = (((wr << 2) + (mi >> 1)) << 3) | ((wc << 1) + (ni >> 1));
      const int ow_ = ((ni & 1) << 10) + (mrow << 6) + ((mi & 1) << 5) + (g << 3);
      u16x4 pk;
      #pragma unroll
      for (int qq = 0; qq < 4; ++qq) pk[qq] = f2bf(acc[mi][ni][qq]);
      *(u16x4*)(smem + (p << 11) + (ow_ ^ ((p & 7) << 4) ^ (((ow_ >> 7) & 7) << 4))) = pk;
    }
  }
  __syncthreads();

  // prefetch nrm + rcp (hidden under stage2)
  f32x4 invn[4];
  #pragma unroll
  for (int pg = 0; pg < 4; ++pg) {
    const int bb = (mb << 3) + (pg << 1) + (g >> 1);
    const f32x4 nv = *(const f32x4*)(nrm + (bb << 8) + (nb << 3) + ((g & 1) << 2));
    #pragma unroll
    for (int qq = 0; qq < 4; ++qq) invn[pg][qq] = __builtin_amdgcn_rcpf(1e-3f + nv[qq]);
  }

  // stage 2: out2[p][f] = sum_k2' opvec[p][k2'] * Wt[f][k2']; wave owns 16 f x 64 p
  const int f0 = w << 4;
  f32x4 acc2[4];
  #pragma unroll
  for (int i = 0; i < 4; ++i) acc2[i] = (f32x4){0.f, 0.f, 0.f, 0.f};
  const unsigned short* wrow = Wt + (size_t)(f0 + mrow) * 1024;
  #pragma unroll 8
  for (int kk2 = 0; kk2 < 32; ++kk2) {
    const bf16x8 b2 = *(const bf16x8*)(wrow + (kk2 << 5) + (g << 3));
    const int orr = (kk2 << 6) + (g << 4);
    #pragma unroll
    for (int pg = 0; pg < 4; ++pg) {
      const int prow = (pg << 4) + mrow;
      const bf16x8 a2 = *(const bf16x8*)(smem + (prow << 11) +
          (orr ^ ((prow & 7) << 4) ^ (((orr >> 7) & 7) << 4)));
      acc2[pg] = __builtin_amdgcn_mfma_f32_16x16x32_bf16(a2, b2, acc2[pg], 0, 0, 0);
    }
  }

  // epilogue: bias, * (1/(eps+norm)), store
  const float ob_ = outb[f0 + mrow];
  #pragma unroll
  for (int pg = 0; pg < 4; ++pg) {
    #pragma unroll
    for (int qq = 0; qq < 4; ++qq) {
      const int p = (pg << 4) + (g << 2) + qq;
      const int bb = (mb << 3) + (p >> 3);
      const int dd = (nb << 3) + (p & 7);
      out[(size_t)((bb << 8) + dd) * 128 + f0 + mrow] = (acc2[pg][qq] + ob_) * invn[pg][qq];
    }
  }
}

extern "C" void kernel_launch(void* const* d_in, const int* in_sizes, int n_in,
                              void* d_out, int out_size, void* d_ws, size_t ws_size,
                              hipStream_t stream) {
  const float* act = (const float*)d_in[0];
  const float* mask = (const float*)d_in[1];
  const float* lns = (const float*)d_in[2];
  const float* lno = (const float*)d_in[3];
  const float* lw = (const float*)d_in[4];
  const float* lb = (const float*)d_in[5];
  const float* rw = (const float*)d_in[6];
  const float* rbv = (const float*)d_in[7];
  const float* ow = (const float*)d_in[8];
  const float* ob = (const float*)d_in[9];
  float* out = (float*)d_out;
  char* ws = (char*)d_ws;

  unsigned short* Lt = (unsigned short*)(ws);               // 8 MB
  unsigned short* Rt = (unsigned short*)(ws + 8388608);     // 8 MB
  unsigned short* Wt = (unsigned short*)(ws + 16777216);    // 256 KB
  unsigned short* wfragG = (unsigned short*)(ws + 17039360);// 32 KB
  float* nrm = (float*)(ws + 17072128);                     // 256 KB

  hipLaunchKernelGGL(prep_k, dim3(512), dim3(256), 0, stream, lw, rw, ow, Wt, wfragG);
  hipLaunchKernelGGL(norm_k, dim3(256), dim3(256), 0, stream, mask, nrm);
  hipLaunchKernelGGL(ln_proj, dim3(8, 256), dim3(256), 0, stream,
                     act, mask, lns, lno, lb, rbv, wfragG, Lt, Rt);
  hipLaunchKernelGGL(gemm_fused, dim3(1024), dim3(512), 0, stream,
                     Lt, Rt, Wt, nrm, ob, out);
}

// Round 6
// 156.711 us; speedup vs baseline: 2.1044x; 1.0122x over previous
//
#include <hip/hip_runtime.h>
#include <hip/hip_bf16.h>
#include <stdint.h>

typedef short bf16x8 __attribute__((ext_vector_type(8)));
typedef float f32x4 __attribute__((ext_vector_type(4)));
typedef float f32x16 __attribute__((ext_vector_type(16)));
typedef unsigned short u16x4 __attribute__((ext_vector_type(4)));
typedef unsigned short u16x8 __attribute__((ext_vector_type(8)));

#define GLOAD16(g, l) __builtin_amdgcn_global_load_lds( \
    (const __attribute__((address_space(1))) void*)(g), \
    (__attribute__((address_space(3))) void*)(l), 16, 0, 0)

__device__ __forceinline__ unsigned short f2bf(float f) {
  unsigned u = __float_as_uint(f);
  unsigned r = (u + 0x7fffu + ((u >> 16) & 1u)) >> 16;
  return (unsigned short)r;
}

// ---------------- prep (+norm merged): Wt[f][k2'] bf16 (k2' = e*32+c);
// wfragG = projection weights in MFMA B-frag order; nrm[b][d] = mask^T mask.
__global__ __launch_bounds__(256) void prep_norm_k(
    const float* __restrict__ lw, const float* __restrict__ rw,
    const float* __restrict__ ow, const float* __restrict__ mask,
    unsigned short* __restrict__ Wt, unsigned short* __restrict__ wfragG,
    float* __restrict__ nrm) {
  const int bid = blockIdx.x;
  if (bid < 512) {
    int idx = bid * 256 + threadIdx.x;
    if (idx < 131072) {
      int f = idx >> 10, k2 = idx & 1023;
      int e = k2 >> 5, c = k2 & 31;
      Wt[idx] = f2bf(ow[(size_t)((c << 5) + e) * 128 + f]);
    }
    if (idx < 16384) {
      int frag = idx >> 9, lane = (idx >> 3) & 63, j = idx & 7;
      int wc = frag >> 4, ni = (frag >> 3) & 1, kk = frag & 7;
      int mrow = lane & 15, g = lane >> 4;
      int c = wc * 32 + ni * 16 + mrow;
      int k = kk * 32 + g * 8 + j;
      wfragG[idx] = f2bf(c < 32 ? lw[k * 32 + c] : rw[k * 32 + (c - 32)]);
    }
  } else {
    const int b = bid - 512, d = threadIdx.x;
    float s = 0.f;
    #pragma unroll 8
    for (int a = 0; a < 512; ++a)
      s += mask[a * 256 + b] * mask[a * 256 + d];
    nrm[(b << 8) + d] = s;
  }
}

// ---------------- fused LayerNorm + projections via MFMA (unchanged from R5)
__global__ __launch_bounds__(256, 4) void ln_proj(
    const float* __restrict__ act, const float* __restrict__ mask,
    const float* __restrict__ lns, const float* __restrict__ lno,
    const float* __restrict__ lb, const float* __restrict__ rb,
    const unsigned short* __restrict__ wfragG,
    unsigned short* __restrict__ Lt, unsigned short* __restrict__ Rt) {
  __shared__ char smem[32768];  // A tile [64 rows][512B swz]; reused as [64c][64a]
  const int tid = threadIdx.x;
  const int lane = tid & 63;
  const int w = tid >> 6;
  const int b = blockIdx.y;
  const int a0 = blockIdx.x << 6;
  const int l = tid & 15;
  const int rg = tid >> 4;

  f32x4 sc[4], of[4];
  #pragma unroll
  for (int j = 0; j < 4; ++j) {
    sc[j] = *(const f32x4*)(lns + (l << 4) + (j << 2));
    of[j] = *(const f32x4*)(lno + (l << 4) + (j << 2));
  }

  #pragma unroll
  for (int i = 0; i < 4; ++i) {
    const int r = rg + (i << 4);
    const float* src = act + ((size_t)(a0 + r) * 256 + b) * 256 + (l << 4);
    f32x4 xv[4];
    #pragma unroll
    for (int j = 0; j < 4; ++j) xv[j] = *(const f32x4*)(src + (j << 2));
    float s = 0.f, sq = 0.f;
    #pragma unroll
    for (int j = 0; j < 4; ++j) {
      f32x4 v = xv[j];
      s += v[0] + v[1] + v[2] + v[3];
      sq += v[0] * v[0] + v[1] * v[1] + v[2] * v[2] + v[3] * v[3];
    }
    s += __shfl_xor(s, 1); sq += __shfl_xor(sq, 1);
    s += __shfl_xor(s, 2); sq += __shfl_xor(sq, 2);
    s += __shfl_xor(s, 4); sq += __shfl_xor(sq, 4);
    s += __shfl_xor(s, 8); sq += __shfl_xor(sq, 8);
    const float mu = s * (1.f / 256.f);
    const float rs = rsqrtf(sq * (1.f / 256.f) - mu * mu + 1e-5f);
    #pragma unroll
    for (int hh = 0; hh < 2; ++hh) {
      u16x8 pk;
      #pragma unroll
      for (int j2 = 0; j2 < 2; ++j2) {
        const int j = (hh << 1) + j2;
        #pragma unroll
        for (int e = 0; e < 4; ++e)
          pk[(j2 << 2) + e] = f2bf((xv[j][e] - mu) * rs * sc[j][e] + of[j][e]);
      }
      const int c = (l << 1) + hh;
      *(u16x8*)(smem + (r << 9) + ((c ^ (r & 7)) << 4)) = pk;
    }
  }
  __syncthreads();

  const int wr = w >> 1, wc = w & 1;
  const int mrow = lane & 15, g = lane >> 4;
  f32x4 acc[2][2];
  #pragma unroll
  for (int i = 0; i < 2; ++i)
    #pragma unroll
    for (int jj = 0; jj < 2; ++jj) acc[i][jj] = (f32x4){0.f, 0.f, 0.f, 0.f};
  #pragma unroll
  for (int kk = 0; kk < 8; ++kk) {
    bf16x8 af[2], bfr[2];
    #pragma unroll
    for (int mi = 0; mi < 2; ++mi) {
      const int row = (wr << 5) + (mi << 4) + mrow;
      af[mi] = *(const bf16x8*)(smem + (row << 9) + ((((kk << 2) + g) ^ (row & 7)) << 4));
    }
    #pragma unroll
    for (int ni = 0; ni < 2; ++ni)
      bfr[ni] = *(const bf16x8*)(wfragG + (size_t)((((wc << 1) + ni) << 3) + kk) * 512 + (lane << 3));
    #pragma unroll
    for (int mi = 0; mi < 2; ++mi)
      #pragma unroll
      for (int ni = 0; ni < 2; ++ni)
        acc[mi][ni] = __builtin_amdgcn_mfma_f32_16x16x32_bf16(af[mi], bfr[ni], acc[mi][ni], 0, 0, 0);
  }
  __syncthreads();

  #pragma unroll
  for (int ni = 0; ni < 2; ++ni) {
    const int c = (wc << 5) + (ni << 4) + mrow;
    const float bias = (wc == 0) ? lb[(ni << 4) + mrow] : rb[(ni << 4) + mrow];
    #pragma unroll
    for (int mi = 0; mi < 2; ++mi) {
      const int aB = (wr << 5) + (mi << 4) + (g << 2);
      u16x4 pk;
      #pragma unroll
      for (int qq = 0; qq < 4; ++qq) {
        const float mk = mask[(size_t)(a0 + aB + qq) * 256 + b];
        pk[qq] = f2bf((acc[mi][ni][qq] + bias) * mk);
      }
      *(u16x4*)(smem + (c << 7) + ((((aB >> 3) & 7) ^ (c & 7)) << 4) + ((aB & 7) << 1)) = pk;
    }
  }
  __syncthreads();

  #pragma unroll
  for (int s = 0; s < 2; ++s) {
    const int c = (w << 4) + (s << 3) + (lane >> 3);
    const int gr = lane & 7;
    const u16x8 v = *(const u16x8*)(smem + (c << 7) + ((gr ^ (c & 7)) << 4));
    unsigned short* dst = (c < 32) ? Lt : Rt;
    *(u16x8*)(dst + (size_t)(b * 32 + (c & 31)) * 512 + a0 + (gr << 3)) = v;
  }
}

// ---------------- main GEMM: 256x256 tile, 8 waves, BK=64, 32x32x16 MFMA.
// 2 barriers/K-tile: {kk-loop reads+MFMA (compiler-interleaved); bar;
// STG x8 (tile t+2, into just-freed cbuf); vmcnt(8); bar}. 2-tile-deep
// prefetch with 2 buffers; never vmcnt(0) in steady state.
// Fused epilogue: op tile -> opvec[64][1024] bf16 (LDS reuse) -> x Wt -> out.
__global__ __launch_bounds__(512, 2) void gemm_fused(
    const unsigned short* __restrict__ Lt, const unsigned short* __restrict__ Rt,
    const unsigned short* __restrict__ Wt, const float* __restrict__ nrm,
    const float* __restrict__ outb, float* __restrict__ out) {
  __shared__ char smem[131072];  // 2 bufs x (A 32KB | B 32KB); reused as opvec
  const int tid = threadIdx.x;
  const int lane = tid & 63;
  const int w = tid >> 6;
  const int wr = w >> 2, wc = w & 3;   // wave owns 128m x 64n
  const int l31 = lane & 31, hi = lane >> 5;
  const int mrow = lane & 15, g = lane >> 4;

  // XCD mapping with L2-octet order (8mb x 4nb per XCD)
  const int bid = blockIdx.x;
  const int xcd = bid & 7, jj_ = bid >> 3;
  const int mb = ((jj_ >> 5) << 3) | (jj_ & 7);
  const int nb = (xcd << 2) | ((jj_ >> 3) & 3);
  const int m0i = mb << 8, n0i = nb << 8;

  const int scol = (((tid & 7) ^ ((tid >> 3) & 7)) << 3);  // pre-swz source col

  f32x16 acc32[4][2];
  #pragma unroll
  for (int i = 0; i < 4; ++i)
    #pragma unroll
    for (int jj = 0; jj < 2; ++jj)
      #pragma unroll
      for (int e = 0; e < 16; ++e) acc32[i][jj][e] = 0.f;

  // STG: one 8KB chunk (64 rows x 128B), linear LDS dest, pre-swz source
  auto STG = [&](const unsigned short* gsrc, int baserow, int dstoff, int kt) {
    GLOAD16(gsrc + ((size_t)(baserow + (tid >> 3)) << 9) + (kt << 6) + scol,
            smem + dstoff + (tid << 4));
  };
  auto STGALL = [&](int buf, int kt) {
    STG(Rt, n0i, buf + 32768, kt);        STG(Rt, n0i + 64, buf + 40960, kt);
    STG(Rt, n0i + 128, buf + 49152, kt);  STG(Rt, n0i + 192, buf + 57344, kt);
    STG(Lt, m0i, buf + 0, kt);            STG(Lt, m0i + 64, buf + 8192, kt);
    STG(Lt, m0i + 128, buf + 16384, kt);  STG(Lt, m0i + 192, buf + 24576, kt);
  };

  // prologue: tiles 0 and 1
  STGALL(0, 0);
  STGALL(65536, 1);
  asm volatile("s_waitcnt vmcnt(8)" ::: "memory");  // tile 0 landed
  __builtin_amdgcn_s_barrier();

  #pragma unroll 1
  for (int t = 0; t < 8; ++t) {
    const char* bufp = smem + ((t & 1) << 16);
    #pragma unroll
    for (int kk = 0; kk < 4; ++kk) {
      bf16x8 af[4], bfv[2];
      #pragma unroll
      for (int Mg = 0; Mg < 4; ++Mg) {
        const int row = (wr << 7) + (Mg << 5) + l31;
        af[Mg] = *(const bf16x8*)(bufp + (row << 7) +
                                  ((((kk << 1) + hi) ^ (row & 7)) << 4));
      }
      #pragma unroll
      for (int Ng = 0; Ng < 2; ++Ng) {
        const int row = (wc << 6) + (Ng << 5) + l31;
        bfv[Ng] = *(const bf16x8*)(bufp + 32768 + (row << 7) +
                                   ((((kk << 1) + hi) ^ (row & 7)) << 4));
      }
      #pragma unroll
      for (int Mg = 0; Mg < 4; ++Mg)
        #pragma unroll
        for (int Ng = 0; Ng < 2; ++Ng)
          acc32[Mg][Ng] = __builtin_amdgcn_mfma_f32_32x32x16_bf16(
              af[Mg], bfv[Ng], acc32[Mg][Ng], 0, 0, 0);
    }
    if (t < 6) {
      __builtin_amdgcn_s_barrier();                  // all reads of cbuf done
      STGALL((t & 1) << 16, t + 2);                  // stage t+2 into cbuf
      asm volatile("s_waitcnt vmcnt(8)" ::: "memory");  // t+1 landed
      __builtin_amdgcn_s_barrier();
    } else if (t == 6) {
      asm volatile("s_waitcnt vmcnt(0)" ::: "memory");  // tile 7 landed
      __builtin_amdgcn_s_barrier();
    }
  }
  __syncthreads();

  // scatter op tile -> opvec[p][k2'] bf16 (p-row 2048B, k2' = e*32+c, dual-XOR swz)
  // 32x32 C/D layout: row32 = (r&3)+8*(r>>2)+4*hi, col = l31.
  #pragma unroll
  for (int Mg = 0; Mg < 4; ++Mg) {
    #pragma unroll
    for (int Ng = 0; Ng < 2; ++Ng) {
      const int p = (((wr << 2) + Mg) << 3) | ((wc << 1) + Ng);
      #pragma unroll
      for (int q = 0; q < 4; ++q) {
        const int c0 = (q << 3) + (hi << 2);
        const int ow_ = (l31 << 6) + (c0 << 1);  // k2*2
        u16x4 pk;
        #pragma unroll
        for (int j = 0; j < 4; ++j) pk[j] = f2bf(acc32[Mg][Ng][(q << 2) + j]);
        *(u16x4*)(smem + (p << 11) +
                  (ow_ ^ ((p & 7) << 4) ^ (((ow_ >> 7) & 7) << 4))) = pk;
      }
    }
  }
  __syncthreads();

  // prefetch nrm + rcp (hidden under stage2)
  f32x4 invn[4];
  #pragma unroll
  for (int pg = 0; pg < 4; ++pg) {
    const int bb = (mb << 3) + (pg << 1) + (g >> 1);
    const f32x4 nv = *(const f32x4*)(nrm + (bb << 8) + (nb << 3) + ((g & 1) << 2));
    #pragma unroll
    for (int qq = 0; qq < 4; ++qq) invn[pg][qq] = __builtin_amdgcn_rcpf(1e-3f + nv[qq]);
  }

  // stage 2: out2[p][f] = sum_k2' opvec[p][k2'] * Wt[f][k2']; wave owns 16 f x 64 p
  const int f0 = w << 4;
  f32x4 acc2[4];
  #pragma unroll
  for (int i = 0; i < 4; ++i) acc2[i] = (f32x4){0.f, 0.f, 0.f, 0.f};
  const unsigned short* wrow = Wt + (size_t)(f0 + mrow) * 1024;
  #pragma unroll 8
  for (int kk2 = 0; kk2 < 32; ++kk2) {
    const bf16x8 b2 = *(const bf16x8*)(wrow + (kk2 << 5) + (g << 3));
    const int orr = (kk2 << 6) + (g << 4);
    #pragma unroll
    for (int pg = 0; pg < 4; ++pg) {
      const int prow = (pg << 4) + mrow;
      const bf16x8 a2 = *(const bf16x8*)(smem + (prow << 11) +
          (orr ^ ((prow & 7) << 4) ^ (((orr >> 7) & 7) << 4)));
      acc2[pg] = __builtin_amdgcn_mfma_f32_16x16x32_bf16(a2, b2, acc2[pg], 0, 0, 0);
    }
  }

  // epilogue: bias, * (1/(eps+norm)), store
  const float ob_ = outb[f0 + mrow];
  #pragma unroll
  for (int pg = 0; pg < 4; ++pg) {
    #pragma unroll
    for (int qq = 0; qq < 4; ++qq) {
      const int p = (pg << 4) + (g << 2) + qq;
      const int bb = (mb << 3) + (p >> 3);
      const int dd = (nb << 3) + (p & 7);
      out[(size_t)((bb << 8) + dd) * 128 + f0 + mrow] = (acc2[pg][qq] + ob_) * invn[pg][qq];
    }
  }
}

extern "C" void kernel_launch(void* const* d_in, const int* in_sizes, int n_in,
                              void* d_out, int out_size, void* d_ws, size_t ws_size,
                              hipStream_t stream) {
  const float* act = (const float*)d_in[0];
  const float* mask = (const float*)d_in[1];
  const float* lns = (const float*)d_in[2];
  const float* lno = (const float*)d_in[3];
  const float* lw = (const float*)d_in[4];
  const float* lb = (const float*)d_in[5];
  const float* rw = (const float*)d_in[6];
  const float* rbv = (const float*)d_in[7];
  const float* ow = (const float*)d_in[8];
  const float* ob = (const float*)d_in[9];
  float* out = (float*)d_out;
  char* ws = (char*)d_ws;

  unsigned short* Lt = (unsigned short*)(ws);               // 8 MB
  unsigned short* Rt = (unsigned short*)(ws + 8388608);     // 8 MB
  unsigned short* Wt = (unsigned short*)(ws + 16777216);    // 256 KB
  unsigned short* wfragG = (unsigned short*)(ws + 17039360);// 32 KB
  float* nrm = (float*)(ws + 17072128);                     // 256 KB

  hipLaunchKernelGGL(prep_norm_k, dim3(768), dim3(256), 0, stream,
                     lw, rw, ow, mask, Wt, wfragG, nrm);
  hipLaunchKernelGGL(ln_proj, dim3(8, 256), dim3(256), 0, stream,
                     act, mask, lns, lno, lb, rbv, wfragG, Lt, Rt);
  hipLaunchKernelGGL(gemm_fused, dim3(1024), dim3(512), 0, stream,
                     Lt, Rt, Wt, nrm, ob, out);
}